// Round 12
// baseline (685.816 us; speedup 1.0000x reference)
//
#include <hip/hip_runtime.h>
#include <stdint.h>

// Problem constants
#define B_ 2
#define T_ 2048
#define S_ 77
#define C_ 1024
#define E_ 4
#define H_ 2816
#define NH_ 8
#define HD_ 128
#define N_ (B_*T_)            // 4096 tokens
#define MAXGB (N_/128 + E_)   // 36 row-tiles of 128 (ffn2_out)
#define MAXGB2 (N_/256 + E_)  // 20 row-tiles of 256 (ffn2_gate)
#define PEsz ((size_t)H_*C_)  // per-expert matrix elems (H*C)
#define CC_ ((size_t)C_*C_)

typedef _Float16 h8 __attribute__((ext_vector_type(8)));
typedef _Float16 h4 __attribute__((ext_vector_type(4)));
typedef float f4 __attribute__((ext_vector_type(4)));

__device__ __forceinline__ void gload16(const void* g, void* l){
  __builtin_amdgcn_global_load_lds((const __attribute__((address_space(1))) void*)g,
                                   (__attribute__((address_space(3))) void*)l, 16, 0, 0);
}

// ---------------- Threefry-2x32 (JAX partitionable) ----------------
__device__ __forceinline__ uint32_t rotl32(uint32_t v, int r){ return (v<<r)|(v>>(32-r)); }
__device__ __forceinline__ void threefry2x32(uint32_t k0, uint32_t k1,
                                             uint32_t x, uint32_t y,
                                             uint32_t& o0, uint32_t& o1){
  uint32_t k2 = k0 ^ k1 ^ 0x1BD11BDAu;
  x += k0; y += k1;
#define TFR(r) { x += y; y = rotl32(y, r); y ^= x; }
  TFR(13) TFR(15) TFR(26) TFR(6)   x += k1; y += k2 + 1u;
  TFR(17) TFR(29) TFR(16) TFR(24)  x += k2; y += k0 + 2u;
  TFR(13) TFR(15) TFR(26) TFR(6)   x += k0; y += k1 + 3u;
  TFR(17) TFR(29) TFR(16) TFR(24)  x += k1; y += k2 + 4u;
  TFR(13) TFR(15) TFR(26) TFR(6)   x += k2; y += k0 + 5u;
#undef TFR
  o0 = x; o1 = y;
}
__device__ __forceinline__ float gumbel_from_bits(uint32_t bits){
  const float TINY = 1.17549435e-38f;
  float f = __uint_as_float((bits >> 9) | 0x3f800000u) - 1.0f;
  float u = fmaxf(TINY, f + TINY);
  return -logf(-logf(u));
}
__device__ __forceinline__ float jax_gumbel(uint32_t k0, uint32_t k1, uint32_t idx){
  uint32_t a, b;
  threefry2x32(k0, k1, 0u, idx, a, b);
  return gumbel_from_bits(a ^ b);
}

// ---------------- conversion job helpers (global-thread-id striding) ----------------
__device__ __forceinline__ void job_split(const float* __restrict__ s,
    _Float16* __restrict__ hi, _Float16* __restrict__ lo, long n4, long gtid, long gstride){
  for (long i = gtid; i < n4; i += gstride){
    float4 v = ((const float4*)s)[i];
    h4 h, L;
    h[0]=(_Float16)v.x; h[1]=(_Float16)v.y; h[2]=(_Float16)v.z; h[3]=(_Float16)v.w;
    L[0]=(_Float16)(v.x-(float)h[0]); L[1]=(_Float16)(v.y-(float)h[1]);
    L[2]=(_Float16)(v.z-(float)h[2]); L[3]=(_Float16)(v.w-(float)h[3]);
    ((h4*)hi)[i] = h; ((h4*)lo)[i] = L;
  }
}
__device__ __forceinline__ void job_plain(const float* __restrict__ s,
    _Float16* __restrict__ d, long n4, long gtid, long gstride){
  for (long i = gtid; i < n4; i += gstride){
    float4 v = ((const float4*)s)[i];
    h4 h;
    h[0]=(_Float16)v.x; h[1]=(_Float16)v.y; h[2]=(_Float16)v.z; h[3]=(_Float16)v.w;
    ((h4*)d)[i] = h;
  }
}
__device__ __forceinline__ void job_w13_plain(const float* __restrict__ w1,
    const float* __restrict__ w3, _Float16* __restrict__ dst, int nslot, long gtid, long gstride){
  const int K8 = C_/8;
  long total = (long)nslot * (2*H_) * K8;
  for (long i = gtid; i < total; i += gstride){
    int kv = (int)(i & (K8-1));
    long rs = i >> 7;
    int r  = (int)(rs % (2*H_));
    int slot = (int)(rs / (2*H_));
    int gg = r >> 5, o = r & 31;
    const float* src = ((o<16)? w1 : w3) + (size_t)slot*PEsz + (size_t)(16*gg + (o&15))*C_ + kv*8;
    float4 v0 = *(const float4*)src, v1 = *(const float4*)(src+4);
    float vv[8] = {v0.x,v0.y,v0.z,v0.w,v1.x,v1.y,v1.z,v1.w};
    h8 hh;
#pragma unroll
    for (int jj=0;jj<8;++jj) hh[jj] = (_Float16)vv[jj];
    *(h8*)(dst + (size_t)slot*2*PEsz + (size_t)r*C_ + kv*8) = hh;
  }
}
__device__ __forceinline__ void job_w13_split_sel(const float* __restrict__ w1,
    const float* __restrict__ w3, int sel0, int sel1,
    _Float16* __restrict__ hi, _Float16* __restrict__ lo, long gtid, long gstride){
  const int K8 = C_/8;
  long total = 2L * (2*H_) * K8;
  for (long i = gtid; i < total; i += gstride){
    int kv = (int)(i & (K8-1));
    long rs = i >> 7;
    int r  = (int)(rs % (2*H_));
    int slot = (int)(rs / (2*H_));
    int e = slot ? sel1 : sel0;
    int gg = r >> 5, o = r & 31;
    const float* src = ((o<16)? w1 : w3) + (size_t)e*PEsz + (size_t)(16*gg + (o&15))*C_ + kv*8;
    float4 v0 = *(const float4*)src, v1 = *(const float4*)(src+4);
    float vv[8] = {v0.x,v0.y,v0.z,v0.w,v1.x,v1.y,v1.z,v1.w};
    h8 hh, ll;
#pragma unroll
    for (int jj=0;jj<8;++jj){
      hh[jj] = (_Float16)vv[jj];
      ll[jj] = (_Float16)(vv[jj]-(float)hh[jj]);
    }
    size_t dof = (size_t)slot*2*PEsz + (size_t)r*C_ + kv*8;
    *(h8*)(hi + dof) = hh;
    *(h8*)(lo + dof) = ll;
  }
}
__device__ __forceinline__ void job_w2_split_sel(const float* __restrict__ w2,
    int sel0, int sel1, _Float16* __restrict__ hi, _Float16* __restrict__ lo, long gtid, long gstride){
  long per = (long)(PEsz/4);
  for (long i = gtid; i < 2*per; i += gstride){
    int slot = (i >= per) ? 1 : 0;
    long ii = i - (long)slot*per;
    float4 v = ((const float4*)(w2 + (size_t)(slot?sel1:sel0)*PEsz))[ii];
    h4 h, L;
    h[0]=(_Float16)v.x; h[1]=(_Float16)v.y; h[2]=(_Float16)v.z; h[3]=(_Float16)v.w;
    L[0]=(_Float16)(v.x-(float)h[0]); L[1]=(_Float16)(v.y-(float)h[1]);
    L[2]=(_Float16)(v.z-(float)h[2]); L[3]=(_Float16)(v.w-(float)h[3]);
    ((h4*)(hi + (size_t)slot*PEsz))[ii] = h;
    ((h4*)(lo + (size_t)slot*PEsz))[ii] = L;
  }
}
// fold_w: Wp[e][k] = sum_c capgw[e][c]*outw[c][k]; bp[e] = sum_c outb[c]*capgw[e][c]
__device__ __forceinline__ void job_foldw(const float* __restrict__ outw,
    const float* __restrict__ capgw, const float* __restrict__ outb,
    float* __restrict__ Wp, float* __restrict__ bp, int b0){
  int e = b0 >> 2;
  int k = ((b0 & 3) << 8) + threadIdx.x;
  const float* cg = capgw + e*C_;
  float acc = 0.f;
  for (int c = 0; c < C_; ++c) acc += cg[c] * outw[(size_t)c*C_ + k];
  Wp[e*C_ + k] = acc;
  if ((b0 & 3) == 0){
    int wv = threadIdx.x >> 6, l = threadIdx.x & 63;
    const float* cg2 = capgw + wv*C_;
    float a2 = 0.f;
    for (int c = l; c < C_; c += 64) a2 += outb[c] * cg2[c];
#pragma unroll
    for (int off = 32; off; off >>= 1) a2 += __shfl_xor(a2, off);
    if (l == 0 && e == 0) bp[wv] = a2;
  }
}

// ---------------- convA: lang gating + phase-0 conversions (w13, w2, x) ----------------
#define CVA_W13 1024
#define CVA_W2  512
#define CVA_X   256
#define CVA_TOT (CVA_W13+CVA_W2+CVA_X)
__global__ __launch_bounds__(256) void convA(
    const float* __restrict__ lang_embed, const float* __restrict__ gate_w,
    const float* __restrict__ gate_b, const int* __restrict__ language,
    const float* __restrict__ w1, const float* __restrict__ w3, const float* __restrict__ w2,
    const float* __restrict__ x,
    _Float16* __restrict__ w13hi, _Float16* __restrict__ w13lo,
    _Float16* __restrict__ w2hi, _Float16* __restrict__ w2lo,
    _Float16* __restrict__ xhi, _Float16* __restrict__ xlo,
    float* __restrict__ langP, int* __restrict__ counts)
{
  __shared__ float lds8[8];
  const int tid = threadIdx.x, w = tid>>6, l = tid&63;
  for (int p = 2*w; p < 2*w+2; ++p){
    int b = p>>2, e = p&3;
    const float* emb = lang_embed + (size_t)language[b]*C_;
    const float* gw  = gate_w + (size_t)e*C_;
    float acc = 0.f;
    for (int c = l; c < C_; c += 64) acc += emb[c]*gw[c];
#pragma unroll
    for (int off = 32; off; off >>= 1) acc += __shfl_xor(acc, off);
    if (l == 0) lds8[p] = acc + gate_b[e];
  }
  __syncthreads();
  int sel[2];
  for (int b = 0; b < 2; ++b){
    float z[4], m = -3.4e38f;
    for (int e = 0; e < 4; ++e){
      float g = jax_gumbel(0u, 1u, (uint32_t)(b*4 + e));
      z[e] = (lds8[b*4 + e] + g) * 0.5f;
      m = fmaxf(m, z[e]);
    }
    float y[4], sum = 0.f;
    for (int e = 0; e < 4; ++e){ y[e] = expf(z[e]-m); sum += y[e]; }
    for (int e = 0; e < 4; ++e) y[e] = y[e] / sum;
    int best = 0; float bv = y[0];
    for (int e = 1; e < 4; ++e) if (y[e] > bv){ bv = y[e]; best = e; }
    sel[b] = best;
    if (blockIdx.x == 0 && tid == 0){
      for (int e = 0; e < 4; ++e)
        langP[b*4 + e] = ((e == best) ? 1.0f : 0.0f) - y[e] + y[e];
    }
  }
  if (blockIdx.x == 0 && tid == 0){
    for (int e = 0; e < 4; ++e) counts[e] = 0;
  }
  int bid = blockIdx.x;
  if (bid < CVA_W13)
    job_w13_split_sel(w1, w3, sel[0], sel[1], w13hi, w13lo,
                      (long)bid*256 + tid, (long)CVA_W13*256);
  else if (bid < CVA_W13+CVA_W2)
    job_w2_split_sel(w2, sel[0], sel[1], w2hi, w2lo,
                     (long)(bid-CVA_W13)*256 + tid, (long)CVA_W2*256);
  else
    job_split(x, xhi, xlo, (long)((size_t)N_*C_/4),
              (long)(bid-CVA_W13-CVA_W2)*256 + tid, (long)CVA_X*256);
}

// ============ deep-pipelined 256x128 split gate GEMM (ffn1_gate) — PURE (r9) ============
__global__ __launch_bounds__(512) void gemm_gate_split(
    const _Float16* __restrict__ Ahi, const _Float16* __restrict__ Alo,
    const _Float16* __restrict__ Bhi, const _Float16* __restrict__ Blo,
    _Float16* __restrict__ Hhi, _Float16* __restrict__ Hlo)
{
  __shared__ __align__(16) char smem[147456];   // 3 x (A 32KB + B 16KB)
  const int tid = threadIdx.x;
  int bid = blockIdx.x;
  {
    int xcd = bid & 7, idx = bid >> 3;
    bid = xcd*88 + idx;
  }
  const int bx = bid / 16, by = bid % 16;
  const int w = tid>>6, l = tid&63;
  const int lm = l&15, g = l>>4;
  const int wm = w>>1, wn = w&1;
  const int n0 = bx<<7;
  const int m0 = by<<8;
  const size_t eoff = (m0 >= T_) ? (size_t)2*PEsz : 0;

  const _Float16* srcA[4]; const _Float16* srcB[2];
#pragma unroll
  for (int jj=0;jj<4;++jj){
    int c = jj*512 + tid, r = c>>3, s = c&7;
    int st = s ^ (r&7);
    srcA[jj] = (st<4 ? Ahi : Alo) + (size_t)(m0 + r)*C_ + ((st&3)<<3);
  }
#pragma unroll
  for (int jj=0;jj<2;++jj){
    int c = jj*512 + tid, r = c>>3, s = c&7;
    int st = s ^ (r&7);
    srcB[jj] = (st<4 ? Bhi : Blo) + eoff + (size_t)(n0 + r)*C_ + ((st&3)<<3);
  }

#define STGF(ts, bi) { \
    int k0 = (ts)<<5; \
    char* db = smem + (bi)*49152; \
    _Pragma("unroll") \
    for (int jj=0;jj<4;++jj) gload16(srcA[jj]+k0, db + (jj*512 + w*64)*16); \
    _Pragma("unroll") \
    for (int jj=0;jj<2;++jj) gload16(srcB[jj]+k0, db + 32768 + (jj*512 + w*64)*16); \
  }

  const int shi = (g ^ (lm&7)) << 4;
  int aoff[4], boff[4];
#pragma unroll
  for (int i=0;i<4;++i){
    aoff[i] = ((wm*64 + i*16 + lm)<<7) + shi;
    boff[i] = 32768 + ((wn*64 + i*16 + lm)<<7) + shi;
  }

  f4 acc[4][4] = {};
  const int nt = C_/32;   // 32
  STGF(0,0) STGF(1,1)
  for (int t=0; t<nt; ++t){
    const int bi = t%3;
    const bool ds = (t+2 < nt);
    const int k2 = (t+2)<<5;
    char* db2 = smem + ((t+2)%3)*49152;
    if (t+1 < nt) { asm volatile("s_waitcnt vmcnt(6)" ::: "memory"); }
    else          { asm volatile("s_waitcnt vmcnt(0)" ::: "memory"); }
    __builtin_amdgcn_s_barrier();
    asm volatile("" ::: "memory");
    const char* base = smem + bi*49152;
    if (ds){
      gload16(srcA[0]+k2, db2 + (0*512 + w*64)*16);
      gload16(srcA[1]+k2, db2 + (1*512 + w*64)*16);
    }
    h8 ah[4], bh[4];
#pragma unroll
    for (int i=0;i<4;++i){ ah[i] = *(const h8*)(base + aoff[i]); bh[i] = *(const h8*)(base + boff[i]); }
    __builtin_amdgcn_s_setprio(1);
#pragma unroll
    for (int mi=0;mi<4;++mi)
#pragma unroll
      for (int ni=0;ni<4;++ni)
        acc[mi][ni] = __builtin_amdgcn_mfma_f32_16x16x32_f16(ah[mi], bh[ni], acc[mi][ni],0,0,0);
    __builtin_amdgcn_s_setprio(0);
    if (ds){
      gload16(srcA[2]+k2, db2 + (2*512 + w*64)*16);
      gload16(srcA[3]+k2, db2 + (3*512 + w*64)*16);
    }
    h8 bl[4];
#pragma unroll
    for (int i=0;i<4;++i) bl[i] = *(const h8*)(base + (boff[i]^64));
    __builtin_amdgcn_s_setprio(1);
#pragma unroll
    for (int mi=0;mi<4;++mi)
#pragma unroll
      for (int ni=0;ni<4;++ni)
        acc[mi][ni] = __builtin_amdgcn_mfma_f32_16x16x32_f16(ah[mi], bl[ni], acc[mi][ni],0,0,0);
    __builtin_amdgcn_s_setprio(0);
    if (ds){
      gload16(srcB[0]+k2, db2 + 32768 + (0*512 + w*64)*16);
      gload16(srcB[1]+k2, db2 + 32768 + (1*512 + w*64)*16);
    }
    h8 al[4];
#pragma unroll
    for (int i=0;i<4;++i) al[i] = *(const h8*)(base + (aoff[i]^64));
    __builtin_amdgcn_s_setprio(1);
#pragma unroll
    for (int mi=0;mi<4;++mi)
#pragma unroll
      for (int ni=0;ni<4;++ni)
        acc[mi][ni] = __builtin_amdgcn_mfma_f32_16x16x32_f16(al[mi], bh[ni], acc[mi][ni],0,0,0);
    __builtin_amdgcn_s_setprio(0);
    asm volatile("" ::: "memory");
  }
#undef STGF

#pragma unroll
  for (int mi=0;mi<4;++mi){
#pragma unroll
    for (int p=0;p<2;++p){
      int hc = ((n0 + wn*64)>>1) + p*16 + lm;
#pragma unroll
      for (int j=0;j<4;++j){
        int rl = wm*64 + mi*16 + (g<<2) + j;
        float s1 = acc[mi][2*p][j], s3 = acc[mi][2*p+1][j];
        float hval = s1/(1.f+expf(-s1))*s3;
        size_t row = (size_t)(m0 + rl);
        _Float16 hh = (_Float16)hval;
        Hhi[row*H_ + hc] = hh;
        Hlo[row*H_ + hc] = (_Float16)(hval - (float)hh);
      }
    }
  }
}

// ============ deep-pipelined 256x128 plain gate GEMM (ffn2_gate) — pure (r9) ============
__global__ __launch_bounds__(512) void gemm_gate_plain(
    const _Float16* __restrict__ A, const _Float16* __restrict__ Bw,
    _Float16* __restrict__ Hout,
    const int* __restrict__ bmap_e, const int* __restrict__ bmap_s,
    const int* __restrict__ offs, const int* __restrict__ perm)
{
  __shared__ __align__(16) char smem[147456];
  const int tid = threadIdx.x, w = tid>>6, l = tid&63;
  const int lm = l&15, g = l>>4;
  const int wm = w>>1, wn = w&1;
  int bx = blockIdx.x, by = blockIdx.y;
  {
    int nx = gridDim.x, ny = gridDim.y;
    int nwg = nx*ny;
    int wg = by*nx + bx;
    int q = nwg >> 3, r = nwg & 7;
    int xcd = wg & 7, idx = wg >> 3;
    int s = (xcd < r ? xcd*(q+1) : r*(q+1) + (xcd-r)*q) + idx;
    bx = s / ny; by = s % ny;
  }
  const int e = bmap_e[by]; if (e<0) return;
  const int m0 = bmap_s[by];
  int v = offs[e+1]-m0; const int valid = v>256?256:v;
  const size_t eoff = (size_t)e*2*PEsz;
  const int n0 = bx<<7;

  const _Float16* srcA[4]; const _Float16* srcB[2];
#pragma unroll
  for (int jj=0;jj<4;++jj){
    int c = jj*512 + tid, r = c>>3, s = c&7;
    int st = s ^ (r&7);
    int ia = m0 + r; ia = (ia<N_) ? ia : (N_-1);
    srcA[jj] = A + (size_t)perm[ia]*C_ + (st<<3);
  }
#pragma unroll
  for (int jj=0;jj<2;++jj){
    int c = jj*512 + tid, r = c>>3, s = c&7;
    int st = s ^ (r&7);
    srcB[jj] = Bw + eoff + (size_t)(n0 + r)*C_ + (st<<3);
  }

#define STGF(ts, bi) { \
    int k0 = (ts)<<6; \
    char* db = smem + (bi)*49152; \
    _Pragma("unroll") \
    for (int jj=0;jj<4;++jj) gload16(srcA[jj]+k0, db + (jj*512 + w*64)*16); \
    _Pragma("unroll") \
    for (int jj=0;jj<2;++jj) gload16(srcB[jj]+k0, db + 32768 + (jj*512 + w*64)*16); \
  }

  const int shi = (g ^ (lm&7)) << 4;
  int aoff[4], boff[4];
#pragma unroll
  for (int i=0;i<4;++i){
    aoff[i] = ((wm*64 + i*16 + lm)<<7) + shi;
    boff[i] = 32768 + ((wn*64 + i*16 + lm)<<7) + shi;
  }

  f4 acc[4][4] = {};
  const int nt = C_/64;   // 16
  STGF(0,0) STGF(1,1)
  for (int t=0; t<nt; ++t){
    const int bi = t%3;
    const bool ds = (t+2 < nt);
    const int k2 = (t+2)<<6;
    char* db2 = smem + ((t+2)%3)*49152;
    if (t+1 < nt) { asm volatile("s_waitcnt vmcnt(6)" ::: "memory"); }
    else          { asm volatile("s_waitcnt vmcnt(0)" ::: "memory"); }
    __builtin_amdgcn_s_barrier();
    asm volatile("" ::: "memory");
    const char* base = smem + bi*49152;
#pragma unroll
    for (int kk=0;kk<2;++kk){
      if (ds){
        if (kk == 0){
          gload16(srcA[0]+k2, db2 + (0*512 + w*64)*16);
          gload16(srcA[1]+k2, db2 + (1*512 + w*64)*16);
          gload16(srcA[2]+k2, db2 + (2*512 + w*64)*16);
        } else {
          gload16(srcA[3]+k2, db2 + (3*512 + w*64)*16);
          gload16(srcB[0]+k2, db2 + 32768 + (0*512 + w*64)*16);
          gload16(srcB[1]+k2, db2 + 32768 + (1*512 + w*64)*16);
        }
      }
      h8 af[4], bf[4];
      const int x = kk<<6;
#pragma unroll
      for (int i=0;i<4;++i){ af[i] = *(const h8*)(base + (aoff[i]^x)); bf[i] = *(const h8*)(base + (boff[i]^x)); }
      __builtin_amdgcn_s_setprio(1);
#pragma unroll
      for (int mi=0;mi<4;++mi)
#pragma unroll
        for (int ni=0;ni<4;++ni)
          acc[mi][ni] = __builtin_amdgcn_mfma_f32_16x16x32_f16(af[mi], bf[ni], acc[mi][ni],0,0,0);
      __builtin_amdgcn_s_setprio(0);
    }
    asm volatile("" ::: "memory");
  }
#undef STGF

#pragma unroll
  for (int mi=0;mi<4;++mi){
#pragma unroll
    for (int p=0;p<2;++p){
      int hc = ((n0 + wn*64)>>1) + p*16 + lm;
#pragma unroll
      for (int j=0;j<4;++j){
        int rl = wm*64 + mi*16 + (g<<2) + j;
        if (rl >= valid) continue;
        float s1 = acc[mi][2*p][j], s3 = acc[mi][2*p+1][j];
        Hout[(size_t)(m0 + rl)*H_ + hc] = (_Float16)(s1/(1.f+expf(-s1))*s3);
      }
    }
  }
}

// ---------------- unified pipelined GEMM body (128x128, r10 single-barrier schedule) ----------------
// NBUF buffers (2 or 3), in-compute staging, ONE barrier per K-step.
template<int EPI, int NSEG, int EXPM, int NBUF>
__device__ __forceinline__ void gemm8_body(
    char* smem,
    const _Float16* __restrict__ A0, const _Float16* __restrict__ A1,
    const _Float16* __restrict__ B0, const _Float16* __restrict__ B1,
    const float* __restrict__ bias, float* __restrict__ Cf32,
    _Float16* __restrict__ O0, _Float16* __restrict__ O1,
    const int* __restrict__ bmap_e, const int* __restrict__ bmap_s,
    const int* __restrict__ offs, const int* __restrict__ perm,
    int M, int K, int Nw, size_t bstride_e, int bx, int by)
{
  const int tid = threadIdx.x, w = tid>>6, l = tid&63;
  const int lm = l&15, g = l>>4;
  const int wm = w>>1, wn = w&1;
  const int n0 = bx<<7;
  int m0, valid = 128; size_t eoff = 0;
  if constexpr (EXPM==3){
    int e = bmap_e[by]; if (e<0) return;
    m0 = bmap_s[by];
    int v = offs[e+1]-m0; valid = v>128?128:v;
    eoff = (size_t)e*bstride_e;
  } else {
    m0 = by<<7;
    if constexpr (EXPM==1) eoff = (m0>=T_) ? bstride_e : 0;
  }
  const int cAe = (((tid&7) ^ ((tid>>3)&7)) << 3);
  size_t rbA[4], rbB[4];
#pragma unroll
  for (int j=0;j<4;++j){
    int r = (j<<5) + (tid>>3);
    int ia = m0 + r;
    if constexpr (EXPM==3){ ia = (ia < N_) ? ia : (N_-1); }
    else { if (ia > M-1) ia = M-1; }
    rbA[j] = (size_t)ia*K + cAe;
    rbB[j] = eoff + (size_t)(n0+r)*K + cAe;
  }
  const int tps = K>>6, nt = NSEG*tps;

#define SEGDEC(tt, kkv, Asrcv, Bsrcv) \
    int sg = 0; \
    if constexpr (NSEG==3){ sg = ((tt)>=2*tps) ? 2 : (((tt)>=tps)?1:0); } \
    const _Float16* Asrcv = (sg==1) ? A1 : A0; \
    const _Float16* Bsrcv = (sg==2) ? B1 : B0; \
    int kkv = ((tt) - sg*tps)<<6;

#define STG_A(tt, cc) { \
    SEGDEC(tt, kk0, Asrc, Bsrc) (void)Bsrc; \
    char* db = smem + (cc)*32768 + w*1024; \
    _Pragma("unroll") \
    for (int j=0;j<4;++j) gload16(Asrc + rbA[j] + kk0, db + j*4096); \
  }
#define STG_B(tt, cc) { \
    SEGDEC(tt, kk0, Asrc, Bsrc) (void)Asrc; \
    char* db = smem + (cc)*32768 + w*1024; \
    _Pragma("unroll") \
    for (int j=0;j<4;++j) gload16(Bsrc + rbB[j] + kk0, db + 16384 + j*4096); \
  }

  int aoff[2][4], boff[2][4];
#pragma unroll
  for (int kk=0;kk<2;++kk){
#pragma unroll
    for (int i=0;i<4;++i){
      int ra = wm*64 + i*16 + lm;
      aoff[kk][i] = (ra<<7) + (((kk<<6)+(g<<4)) ^ ((ra&7)<<4));
      int rb = wn*64 + i*16 + lm;
      boff[kk][i] = (rb<<7) + (((kk<<6)+(g<<4)) ^ ((rb&7)<<4));
    }
  }

  f4 acc[4][4] = {};
  STG_A(0,0) STG_B(0,0)
  if constexpr (NBUF==3){ STG_A(1,1) STG_B(1,1) }
  for (int t=0; t<nt; ++t){
    const int rb = t % NBUF;
    const int ts = t + NBUF - 1;
    const bool ds = ts < nt;
    const int wbuf = ts % NBUF;
    if (t+1 < nt){
      if constexpr (NBUF==3) asm volatile("s_waitcnt vmcnt(8)" ::: "memory");
      else                   asm volatile("s_waitcnt vmcnt(0)" ::: "memory");
    } else {
      asm volatile("s_waitcnt vmcnt(0)" ::: "memory");
    }
    __builtin_amdgcn_s_barrier();
    asm volatile("" ::: "memory");
    const char* Ab = smem + rb*32768;
    const char* Bb = Ab + 16384;
    if (ds) STG_A(ts, wbuf)
    {
      h8 af[4], bf[4];
#pragma unroll
      for (int i=0;i<4;++i){
        af[i] = *(const h8*)(Ab + aoff[0][i]);
        bf[i] = *(const h8*)(Bb + boff[0][i]);
      }
      __builtin_amdgcn_s_setprio(1);
#pragma unroll
      for (int mi=0;mi<4;++mi)
#pragma unroll
        for (int ni=0;ni<4;++ni)
          acc[mi][ni] = __builtin_amdgcn_mfma_f32_16x16x32_f16(af[mi], bf[ni], acc[mi][ni],0,0,0);
      __builtin_amdgcn_s_setprio(0);
    }
    if (ds) STG_B(ts, wbuf)
    {
      h8 af[4], bf[4];
#pragma unroll
      for (int i=0;i<4;++i){
        af[i] = *(const h8*)(Ab + aoff[1][i]);
        bf[i] = *(const h8*)(Bb + boff[1][i]);
      }
      __builtin_amdgcn_s_setprio(1);
#pragma unroll
      for (int mi=0;mi<4;++mi)
#pragma unroll
        for (int ni=0;ni<4;++ni)
          acc[mi][ni] = __builtin_amdgcn_mfma_f32_16x16x32_f16(af[mi], bf[ni], acc[mi][ni],0,0,0);
      __builtin_amdgcn_s_setprio(0);
    }
    asm volatile("" ::: "memory");
  }

#pragma unroll
  for (int mi=0;mi<4;++mi){
    const int rl0 = wm*64 + mi*16 + (g<<2);
#pragma unroll
    for (int ni=0;ni<4;++ni){
      int col = n0 + wn*64 + ni*16 + lm;
#pragma unroll
      for (int j=0;j<4;++j){
        int rl = rl0 + j;
        float vv = acc[mi][ni][j];
        if constexpr (EPI==1){
          int grow = m0 + rl;
          if (grow < M){
            float vb = vv + (bias ? bias[col] : 0.f);
            _Float16 hh = (_Float16)vb;
            O0[(size_t)grow*Nw + col] = hh;
            O1[(size_t)grow*Nw + col] = (_Float16)(vb - (float)hh);
          }
        } else {
          if (rl < valid){
            int orig = perm[m0 + rl];
            size_t o = (size_t)orig*C_ + col;
            Cf32[o] = (float)O0[o] + (float)O1[o] + vv;
          }
        }
      }
    }
  }
#undef STG_A
#undef STG_B
#undef SEGDEC
}

// ---------------- ffn1_out (NBUF=2, 64KB) + phase-2 conversion riders (r9 placement) ----------------
__global__ __launch_bounds__(256) void ffn1_out_fused(
    const _Float16* __restrict__ Hbh, const _Float16* __restrict__ Hbl,
    const _Float16* __restrict__ w2hi, const _Float16* __restrict__ w2lo,
    _Float16* __restrict__ Fh, _Float16* __restrict__ Fl,
    const float* __restrict__ in_w,
    const float* __restrict__ cap_w1, const float* __restrict__ cap_w3,
    const float* __restrict__ caption,
    _Float16* __restrict__ inwh, _Float16* __restrict__ inwl,
    _Float16* __restrict__ capw13,
    _Float16* __restrict__ caph, _Float16* __restrict__ capl)
{
  __shared__ __align__(16) char smem[65536];
  int id = blockIdx.x;
  if (id < 256){
    gemm8_body<1,3,1,2>(smem, Hbh, Hbl, w2hi, w2lo, nullptr, nullptr, Fh, Fl,
                        nullptr,nullptr,nullptr,nullptr, N_, H_, C_, PEsz, id&7, id>>3);
  } else {
    int cid = id - 256;                    // 512 conversion riders (2/CU co-resident)
    if (cid < 352)      job_w13_plain(cap_w1, cap_w3, capw13, 4, (long)cid*256 + threadIdx.x, 352L*256);
    else if (cid < 496) job_split(in_w, inwh, inwl, (long)(3*CC_/4), (long)(cid-352)*256 + threadIdx.x, 144L*256);
    else                job_split(caption, caph, capl, (long)((size_t)B_*S_*C_/4), (long)(cid-496)*256 + threadIdx.x, 16L*256);
  }
}

// ---------------- Q + KV projections + fold_w (304 blocks, no heavy riders) ----------------
__global__ __launch_bounds__(256) void gemm_qkv(
    const _Float16* __restrict__ Fh, const _Float16* __restrict__ Fl,
    const _Float16* __restrict__ caph, const _Float16* __restrict__ capl,
    const _Float16* __restrict__ inwh, const _Float16* __restrict__ inwl,
    const float* __restrict__ in_b,
    _Float16* __restrict__ Qh, _Float16* __restrict__ Ql,
    _Float16* __restrict__ KVh, _Float16* __restrict__ KVl,
    const float* __restrict__ out_w, const float* __restrict__ cap_gw,
    const float* __restrict__ out_b, float* __restrict__ Wp, float* __restrict__ bp)
{
  __shared__ __align__(16) char smem[65536];
  int id = blockIdx.x;
  if (id < 256){
    gemm8_body<1,3,0,2>(smem, Fh, Fl, inwh, inwl, in_b, nullptr, Qh, Ql,
                        nullptr,nullptr,nullptr,nullptr, N_, C_, C_, 0, id&7, id>>3);
  } else if (id < 288){
    int cid = id - 256;
    gemm8_body<1,3,0,2>(smem, caph, capl, inwh + CC_, inwl + CC_, in_b + C_,
                        nullptr, KVh, KVl, nullptr,nullptr,nullptr,nullptr,
                        B_*S_, C_, 2*C_, 0, cid & 15, cid >> 4);
  } else {
    job_foldw(out_w, cap_gw, out_b, Wp, bp, id-288);
  }
}

// ---------------- MFMA cross attention + capw2 riders (640 blocks, r9 placement) ----------------
#define SP5 5
#define KSTR 136
#define VSTR 104
__global__ __launch_bounds__(256) void attn_fused(
    const _Float16* __restrict__ Qh, const _Float16* __restrict__ Ql,
    const _Float16* __restrict__ KVh, const _Float16* __restrict__ KVl,
    _Float16* __restrict__ AOh, _Float16* __restrict__ AOl,
    const float* __restrict__ cap_w2, _Float16* __restrict__ capw2f)
{
  __shared__ __align__(16) _Float16 Usm[2*128*VSTR];
  __shared__ __align__(16) _Float16 Psm[2*64*VSTR];
  int id = blockIdx.x;
  if (id >= 512){
    job_plain(cap_w2, capw2f, (long)(4*PEsz/4), (long)(id-512)*256 + threadIdx.x, 128L*256);
    return;
  }
  _Float16* Kh_s = Usm;
  _Float16* Kl_s = Usm + 128*VSTR;
  _Float16* VTh  = Usm;
  _Float16* VTl  = Usm + 128*VSTR;
  _Float16* Ph   = Psm;
  _Float16* Pl   = Psm + 64*VSTR;

  const int tid = threadIdx.x;
  const int w = tid>>6, l = tid&63, lm = l&15, g = l>>4;
  const int b = id >> 8, h = (id >> 5) & 7, q0 = (id & 31) << 6;
  const float scale = 0.08838834764831845f;

  for (int i = tid; i < 64*VSTR; i += 256) ((uint32_t*)Psm)[i] = 0;
  {
    int oct = tid & 15, s0 = tid >> 4;
    for (int s = s0; s < 80; s += 16){
      h8 vh = {}, vl = {};
      if (s < S_){
        size_t ga = ((size_t)(b*S_ + s))*(2*C_) + h*HD_ + oct*8;
        vh = *(const h8*)(KVh + ga);
        vl = *(const h8*)(KVl + ga);
      }
      *(h8*)(Kh_s + s*KSTR + oct*8) = vh;
      *(h8*)(Kl_s + s*KSTR + oct*8) = vl;
    }
  }
  h8 qh[4], ql[4];
  {
    size_t qrow = (size_t)(b*T_ + q0 + w*16 + lm);
    const _Float16* qph = Qh + qrow*C_ + h*HD_ + g*8;
    const _Float16* qpl = Ql + qrow*C_ + h*HD_ + g*8;
#pragma unroll
    for (int ks=0; ks<4; ++ks){ qh[ks] = *(const h8*)(qph + ks*32); ql[ks] = *(const h8*)(qpl + ks*32); }
  }
  __syncthreads();

  f4 sc[SP5] = {};
#pragma unroll
  for (int ks=0; ks<4; ++ks){
#pragma unroll
    for (int nt=0; nt<SP5; ++nt){
      h8 kh = *(const h8*)(Kh_s + (nt*16+lm)*KSTR + ks*32 + g*8);
      h8 kl = *(const h8*)(Kl_s + (nt*16+lm)*KSTR + ks*32 + g*8);
      sc[nt] = __builtin_amdgcn_mfma_f32_16x16x32_f16(qh[ks], kh, sc[nt],0,0,0);
      sc[nt] = __builtin_amdgcn_mfma_f32_16x16x32_f16(ql[ks], kh, sc[nt],0,0,0);
      sc[nt] = __builtin_amdgcn_mfma_f32_16x16x32_f16(qh[ks], kl, sc[nt],0,0,0);
    }
  }

  float mx[4] = {-3e38f,-3e38f,-3e38f,-3e38f};
#pragma unroll
  for (int nt=0; nt<SP5; ++nt){
    bool valid = (nt*16+lm) < S_;
#pragma unroll
    for (int j=0;j<4;++j){
      float v = valid ? sc[nt][j]*scale : -3e38f;
      sc[nt][j] = v;
      mx[j] = fmaxf(mx[j], v);
    }
  }
#pragma unroll
  for (int off=1; off<16; off<<=1){
#pragma unroll
    for (int j=0;j<4;++j) mx[j] = fmaxf(mx[j], __shfl_xor(mx[j], off));
  }
  float sm[4] = {0,0,0,0};
#pragma unroll
  for (int nt=0; nt<SP5; ++nt){
    bool valid = (nt*16+lm) < S_;
#pragma unroll
    for (int j=0;j<4;++j){
      float p = valid ? expf(sc[nt][j]-mx[j]) : 0.f;
      sc[nt][j] = p; sm[j] += p;
    }
  }
#pragma unroll
  for (int off=1; off<16; off<<=1){
#pragma unroll
    for (int j=0;j<4;++j) sm[j] += __shfl_xor(sm[j], off);
  }
#pragma unroll
  for (int nt=0; nt<SP5; ++nt){
#pragma unroll
    for (int j=0;j<4;++j){
      int col = nt*16 + lm;
      if (col < S_){
        float p = sc[nt][j] / sm[j];
        int row = w*16 + g*4 + j;
        _Float16 ph = (_Float16)p;
        Ph[row*VSTR + col] = ph;
        Pl[row*VSTR + col] = (_Float16)(p - (float)ph);
      }
    }
  }
  __syncthreads();

  for (int i = tid; i < 128*VSTR; i += 256) ((uint32_t*)Usm)[i] = 0;
  __syncthreads();
  {
    int oct = tid & 15, s0 = tid >> 4;
    for (int s = s0; s < S_; s += 16){
      size_t ga = ((size_t)(b*S_ + s))*(2*C_) + C_ + h*HD_ + oct*8;
      h8 vh = *(const h8*)(KVh + ga);
      h8 vl = *(const h8*)(KVl + ga);
#pragma unroll
      for (int i2=0;i2<8;++i2){
        VTh[(oct*8+i2)*VSTR + s] = vh[i2];
        VTl[(oct*8+i2)*VSTR + s] = vl[i2];
      }
    }
  }
  __syncthreads();

  h8 pah[3], pal[3];
#pragma unroll
  for (int ks=0;ks<3;++ks){
    pah[ks] = *(const h8*)(Ph + (w*16+lm)*VSTR + ks*32 + g*8);
    pal[ks] = *(const h8*)(Pl + (w*16+lm)*VSTR + ks*32 + g*8);
  }
#pragma unroll
  for (int nt=0; nt<8; ++nt){
    f4 o = {};
#pragma unroll
    for (int ks=0;ks<3;++ks){
      h8 vh = *(const h8*)(VTh + (nt*16+lm)*VSTR + ks*32 + g*8);
      h8 vl = *(const h8*)(VTl + (nt*16+lm)*VSTR + ks*32 + g*8);
      o = __builtin_amdgcn_mfma_f32_16x16x32_f16(pah[ks], vh, o,0,0,0);
      o = __builtin_amdgcn_mfma_f32_16x16x32_f16(pal[ks], vh, o,0,0,0);
      o = __builtin_amdgcn_mfma_f32_16x16x32_f16(pah[ks], vl, o,0,0,0);
    }
#pragma unroll
    for (int j=0;j<4;++j){
      size_t orow = (size_t)(b*T_ + q0 + w*16 + g*4 + j);
      size_t oa = orow*C_ + h*HD_ + nt*16 + lm;
      _Float16 hh = (_Float16)o[j];
      AOh[oa] = hh;
      AOl[oa] = (_Float16)(o[j] - (float)hh);
    }
  }
}

// ---------------- caption gating from AO (hi/lo) via folded W' ----------------
__global__ __launch_bounds__(256) void cap_gate(
    const _Float16* __restrict__ AOh, const _Float16* __restrict__ AOl,
    const float* __restrict__ Wp, const float* __restrict__ bp,
    const float* __restrict__ gb,
    int* __restrict__ cap_sel, float* __restrict__ capP, int* __restrict__ counts)
{
  int tid = threadIdx.x, wave = tid >> 6, lane = tid & 63;
  for (int r = 0; r < 2; ++r){
    int row = (blockIdx.x << 3) + (wave << 1) + r;
    float av[16];
#pragma unroll
    for (int i = 0; i < 16; ++i){
      int c = lane + (i << 6);
      av[i] = (float)AOh[(size_t)row*C_ + c] + (float)AOl[(size_t)row*C_ + c];
    }
    float lg[E_];
#pragma unroll
    for (int e = 0; e < E_; ++e){
      const float* wv = Wp + (size_t)e * C_;
      float p = 0.f;
#pragma unroll
      for (int i = 0; i < 16; ++i) p += av[i] * wv[lane + (i << 6)];
#pragma unroll
      for (int off = 32; off; off >>= 1) p += __shfl_xor(p, off);
      lg[e] = p + bp[e] + gb[e];
    }
    if (lane == 0){
      float z[E_], m = -3.4e38f;
      for (int e = 0; e < E_; ++e){
        float gmb = jax_gumbel(0u, 2u, (uint32_t)(row*E_ + e));
        z[e] = (lg[e] + gmb) * 0.5f;
        m = fmaxf(m, z[e]);
      }
      float y[E_], sum = 0.f;
      for (int e = 0; e < E_; ++e){ y[e] = expf(z[e] - m); sum += y[e]; }
      for (int e = 0; e < E_; ++e) y[e] = y[e] / sum;
      int best = 0; float bv = y[0];
      for (int e = 1; e < E_; ++e) if (y[e] > bv){ bv = y[e]; best = e; }
      cap_sel[row] = best;
      atomicAdd(&counts[best], 1);
      for (int e = 0; e < E_; ++e)
        capP[(size_t)row*E_ + e] = ((e == best) ? 1.0f : 0.0f) - y[e] + y[e];
    }
  }
}

// ---------------- finalize: groups + perm scatter (block 0) + loss (block 1) ----------------
__global__ __launch_bounds__(256) void finalize(
    const int* __restrict__ counts, const int* __restrict__ cap_sel,
    int* __restrict__ offs,
    int* __restrict__ bmap_e, int* __restrict__ bmap_s,
    int* __restrict__ bmap_e2, int* __restrict__ bmap_s2,
    int* __restrict__ perm,
    const float* __restrict__ capP, const float* __restrict__ langP,
    float* __restrict__ out_loss)
{
  __shared__ int loffs[5];
  __shared__ int lcur[4];
  __shared__ float red[4][256];
  int tid = threadIdx.x;
  if (blockIdx.x == 0){
    if (tid == 0){
      loffs[0] = 0;
      for (int e = 0; e < E_; ++e){ loffs[e+1] = loffs[e] + counts[e]; lcur[e] = loffs[e]; }
      for (int e = 0; e < E_+1; ++e) offs[e] = loffs[e];
      int idx = 0;
      for (int e = 0; e < E_; ++e)
        for (int s = loffs[e]; s < loffs[e+1]; s += 128){ bmap_e[idx] = e; bmap_s[idx] = s; ++idx; }
      for (; idx < MAXGB; ++idx) bmap_e[idx] = -1;
      int idx2 = 0;
      for (int e = 0; e < E_; ++e)
        for (int s = loffs[e]; s < loffs[e+1]; s += 256){ bmap_e2[idx2] = e; bmap_s2[idx2] = s; ++idx2; }
      for (; idx2 < MAXGB2; ++idx2) bmap_e2[idx2] = -1;
    }
    __syncthreads();
    for (int row = tid; row < N_; row += 256){
      int e = cap_sel[row];
      int pos = atomicAdd(&lcur[e], 1);
      perm[pos] = row;
    }
  } else {
    float p0=0.f, p1=0.f, p2=0.f, p3=0.f;
    for (int r = tid; r < N_; r += 256){
      const float* p = capP + (size_t)r*E_;
      p0 += p[0]; p1 += p[1]; p2 += p[2]; p3 += p[3];
    }
    red[0][tid]=p0; red[1][tid]=p1; red[2][tid]=p2; red[3][tid]=p3;
    __syncthreads();
    for (int s = 128; s > 0; s >>= 1){
      if (tid < s){
        red[0][tid]+=red[0][tid+s]; red[1][tid]+=red[1][tid+s];
        red[2][tid]+=red[2][tid+s]; red[3][tid]+=red[3][tid+s];
      }
      __syncthreads();
    }
    if (tid == 0){
      float loss = 0.f;
      for (int e = 0; e < E_; ++e){
        float ul = (langP[e] + langP[E_ + e]) * 0.5f;
        loss += ul * logf(ul + 1e-10f);
      }
      for (int e = 0; e < E_; ++e){
        float uc = red[e][0] * (1.0f / N_);
        loss += uc * logf(uc + 1e-10f);
      }
      out_loss[0] = loss;
    }
  }
}

// ---------------- ffn2_out wrapper (NBUF=2) ----------------
__global__ __launch_bounds__(256) void ffn2_out(
    const _Float16* __restrict__ H2, const _Float16* __restrict__ capw2f,
    float* __restrict__ out,
    const _Float16* __restrict__ Fh, const _Float16* __restrict__ Fl,
    const int* __restrict__ bmap_e, const int* __restrict__ bmap_s,
    const int* __restrict__ offs, const int* __restrict__ perm)
{
  __shared__ __align__(16) char smem[65536];
  int bx = blockIdx.x, by = blockIdx.y;
  {
    int nx = gridDim.x, ny = gridDim.y;
    int nwg = nx*ny;
    int wg = by*nx + bx;
    int q = nwg >> 3, r = nwg & 7;
    int xcd = wg & 7, idx = wg >> 3;
    int s = (xcd < r ? xcd*(q+1) : r*(q+1) + (xcd-r)*q) + idx;
    bx = s / ny; by = s % ny;
  }
  gemm8_body<2,1,3,2>(smem, H2, nullptr, capw2f, nullptr, nullptr, out,
                      (_Float16*)Fh, (_Float16*)Fl,
                      bmap_e, bmap_s, offs, perm, N_, H_, C_, PEsz, bx, by);
}

// ---------------- host launch ----------------
extern "C" void kernel_launch(void* const* d_in, const int* in_sizes, int n_in,
                              void* d_out, int out_size, void* d_ws, size_t ws_size,
                              hipStream_t stream)
{
  const float* x          = (const float*)d_in[0];
  const float* caption    = (const float*)d_in[2];
  const int*   language   = (const int*)  d_in[3];
  const float* lang_embed = (const float*)d_in[4];
  const float* lang_gw    = (const float*)d_in[5];
  const float* lang_gb    = (const float*)d_in[6];
  const float* lang_w1    = (const float*)d_in[7];
  const float* lang_w2    = (const float*)d_in[8];
  const float* lang_w3    = (const float*)d_in[9];
  const float* in_w       = (const float*)d_in[10];
  const float* in_b       = (const float*)d_in[11];
  const float* out_w      = (const float*)d_in[12];
  const float* out_b      = (const float*)d_in[13];
  const float* cap_gw     = (const float*)d_in[14];
  const float* cap_gb     = (const float*)d_in[15];
  const float* cap_w1     = (const float*)d_in[16];
  const float* cap_w2     = (const float*)d_in[17];
  const float* cap_w3     = (const float*)d_in[18];
  float* out = (float*)d_out;

  const size_t NC = (size_t)N_*C_;
  const size_t NHe = (size_t)N_*H_;
  const size_t KVel = (size_t)B_*S_*2*C_;
  const size_t CAPel = (size_t)B_*S_*C_;

  char* base = (char*)d_ws;
  size_t cur = 0;
  auto alloc = [&](size_t bytes)->char*{
    char* p = base + cur;
    cur += (bytes + 255) & ~(size_t)255;
    return p;
  };
  _Float16* Qh = (_Float16*)alloc(NC*2);
  _Float16* Ql = (_Float16*)alloc(NC*2);
  char* kvreg = alloc(KVel*4);
  _Float16* KVh = (_Float16*)kvreg;
  _Float16* KVl = KVh + KVel;
  float* capP   = (float*)alloc((size_t)N_*E_*4);
  float* langP  = (float*)alloc(64);
  float* Wp     = (float*)alloc(E_*C_*4);
  float* bp     = (float*)alloc(64);
  int* cap_sel  = (int*)alloc(N_*4);
  int* counts   = (int*)alloc(64);
  int* offs     = (int*)alloc(64);
  int* bmap_e   = (int*)alloc(MAXGB*4);
  int* bmap_s   = (int*)alloc(MAXGB*4);
  int* bmap_e2  = (int*)alloc(MAXGB2*4);
  int* bmap_s2  = (int*)alloc(MAXGB2*4);
  int* perm     = (int*)alloc(N_*4);
  _Float16* xAO_hi = (_Float16*)alloc(NC*2);      // x_hi, then AO_hi
  _Float16* xAO_lo = (_Float16*)alloc(NC*2);
  _Float16* cap_hi = (_Float16*)alloc(CAPel*2);
  _Float16* cap_lo = (_Float16*)alloc(CAPel*2);
  _Float16* Hb_hi  = (_Float16*)alloc(NHe*2);     // stage-1 hidden hi, then H2
  _Float16* Hb_lo  = (_Float16*)alloc(NHe*2);
  _Float16* F_hi   = (_Float16*)alloc(NC*2);
  _Float16* F_lo   = (_Float16*)alloc(NC*2);
  _Float16* Wreg = (_Float16*)alloc(2*( (size_t)3*CC_*2 + CC_*2 + 3*4*PEsz ));
  // phase-1 (lang): w13 split [0,8P), w2 split [8P,12P)
  _Float16* w13hi = Wreg;
  _Float16* w13lo = Wreg + 4*PEsz;
  _Float16* w2hi  = Wreg + 8*PEsz;
  _Float16* w2lo  = Wreg + 10*PEsz;
  // phase-2 in FRESH regions (written by riders while w13/w2 still live — no overlay):
  _Float16* inw_hi  = Wreg + 12*PEsz;
  _Float16* inw_lo  = inw_hi + 3*CC_;
  _Float16* capw13f = Wreg + 12*PEsz + 6*CC_;       // 8*PEsz
  _Float16* capw2f  = capw13f + 8*PEsz;             // 4*PEsz

  // 1) phase-0 conversions (+ inline language gating)
  convA<<<CVA_TOT, 256, 0, stream>>>(
      lang_embed, lang_gw, lang_gb, language,
      lang_w1, lang_w3, lang_w2, x,
      w13hi, w13lo, w2hi, w2lo, xAO_hi, xAO_lo, langP, counts);

  // 2) ffn1 gate (PURE — 147KB LDS = 1 block/CU)
  gemm_gate_split<<<704, 512, 0, stream>>>(
      xAO_hi, xAO_lo, w13hi, w13lo, Hb_hi, Hb_lo);

  // 3) ffn1 out (NBUF=2, 64KB = 2 blocks/CU) + capw13/inw/caption riders
  ffn1_out_fused<<<768, 256, 0, stream>>>(
      Hb_hi, Hb_lo, w2hi, w2lo, F_hi, F_lo,
      in_w, cap_w1, cap_w3, caption,
      inw_hi, inw_lo, capw13f, cap_hi, cap_lo);

  // 4) Q + KV projections + fold_w
  gemm_qkv<<<304, 256, 0, stream>>>(
      F_hi, F_lo, cap_hi, cap_lo, inw_hi, inw_lo, in_b,
      Qh, Ql, KVh, KVl, out_w, cap_gw, out_b, Wp, bp);

  // 5) attention + capw2 riders
  attn_fused<<<640, 256, 0, stream>>>(Qh, Ql, KVh, KVl, xAO_hi, xAO_lo, cap_w2, capw2f);

  // 6) caption gating directly from AO via W'
  cap_gate<<<N_/8, 256, 0, stream>>>(xAO_hi, xAO_lo, Wp, bp, cap_gb, cap_sel, capP, counts);

  // 7) groups + perm + loss
  finalize<<<2, 256, 0, stream>>>(counts, cap_sel, offs, bmap_e, bmap_s,
                                  bmap_e2, bmap_s2, perm, capP, langP, out + NC);

  // 8) ffn2 gate
  _Float16* H2 = Hb_hi;
  gemm_gate_plain<<<dim3((2*H_)/128, MAXGB2), 512, 0, stream>>>(
      F_hi, capw13f, H2, bmap_e2, bmap_s2, offs, perm);

  // 9) ffn2 out + final sum scatter
  ffn2_out<<<dim3(C_/128, MAXGB), 256, 0, stream>>>(
      H2, capw2f, out, F_hi, F_lo, bmap_e, bmap_s, offs, perm);
}

// Round 13
// 641.431 us; speedup vs baseline: 1.0692x; 1.0692x over previous
//
#include <hip/hip_runtime.h>
#include <stdint.h>

// Problem constants
#define B_ 2
#define T_ 2048
#define S_ 77
#define C_ 1024
#define E_ 4
#define H_ 2816
#define NH_ 8
#define HD_ 128
#define N_ (B_*T_)            // 4096 tokens
#define MAXGB (N_/128 + E_)   // 36 row-tiles of 128 (ffn2_out)
#define MAXGB2 (N_/256 + E_)  // 20 row-tiles of 256 (ffn2_gate)
#define PEsz ((size_t)H_*C_)  // per-expert matrix elems (H*C)
#define CC_ ((size_t)C_*C_)

typedef _Float16 h8 __attribute__((ext_vector_type(8)));
typedef _Float16 h4 __attribute__((ext_vector_type(4)));
typedef float f4 __attribute__((ext_vector_type(4)));

__device__ __forceinline__ void gload16(const void* g, void* l){
  __builtin_amdgcn_global_load_lds((const __attribute__((address_space(1))) void*)g,
                                   (__attribute__((address_space(3))) void*)l, 16, 0, 0);
}

// bijective XCD chunking, COLUMN-major decode
__device__ __forceinline__ void xcd_swizzle_cm(int& bx, int& by){
  int nx = gridDim.x, ny = gridDim.y;
  int nwg = nx*ny;
  int wg = by*nx + bx;
  int q = nwg >> 3, r = nwg & 7;
  int xcd = wg & 7, idx = wg >> 3;
  int s = (xcd < r ? xcd*(q+1) : r*(q+1) + (xcd-r)*q) + idx;
  bx = s / ny; by = s % ny;
}

// ---------------- Threefry-2x32 (JAX partitionable) ----------------
__device__ __forceinline__ uint32_t rotl32(uint32_t v, int r){ return (v<<r)|(v>>(32-r)); }
__device__ __forceinline__ void threefry2x32(uint32_t k0, uint32_t k1,
                                             uint32_t x, uint32_t y,
                                             uint32_t& o0, uint32_t& o1){
  uint32_t k2 = k0 ^ k1 ^ 0x1BD11BDAu;
  x += k0; y += k1;
#define TFR(r) { x += y; y = rotl32(y, r); y ^= x; }
  TFR(13) TFR(15) TFR(26) TFR(6)   x += k1; y += k2 + 1u;
  TFR(17) TFR(29) TFR(16) TFR(24)  x += k2; y += k0 + 2u;
  TFR(13) TFR(15) TFR(26) TFR(6)   x += k0; y += k1 + 3u;
  TFR(17) TFR(29) TFR(16) TFR(24)  x += k1; y += k2 + 4u;
  TFR(13) TFR(15) TFR(26) TFR(6)   x += k2; y += k0 + 5u;
#undef TFR
  o0 = x; o1 = y;
}
__device__ __forceinline__ float gumbel_from_bits(uint32_t bits){
  const float TINY = 1.17549435e-38f;
  float f = __uint_as_float((bits >> 9) | 0x3f800000u) - 1.0f;
  float u = fmaxf(TINY, f + TINY);
  return -logf(-logf(u));
}
__device__ __forceinline__ float jax_gumbel(uint32_t k0, uint32_t k1, uint32_t idx){
  uint32_t a, b;
  threefry2x32(k0, k1, 0u, idx, a, b);
  return gumbel_from_bits(a ^ b);
}

// ---------------- conversion job helpers (grid-stride over nb blocks) ----------------
__device__ __forceinline__ void job_split(const float* __restrict__ s,
    _Float16* __restrict__ hi, _Float16* __restrict__ lo, long n4, int b0, int nb){
  for (long i = (long)b0*256 + threadIdx.x; i < n4; i += (long)nb*256){
    float4 v = ((const float4*)s)[i];
    h4 h, L;
    h[0]=(_Float16)v.x; h[1]=(_Float16)v.y; h[2]=(_Float16)v.z; h[3]=(_Float16)v.w;
    L[0]=(_Float16)(v.x-(float)h[0]); L[1]=(_Float16)(v.y-(float)h[1]);
    L[2]=(_Float16)(v.z-(float)h[2]); L[3]=(_Float16)(v.w-(float)h[3]);
    ((h4*)hi)[i] = h; ((h4*)lo)[i] = L;
  }
}
__device__ __forceinline__ void job_plain(const float* __restrict__ s,
    _Float16* __restrict__ d, long n4, int b0, int nb){
  for (long i = (long)b0*256 + threadIdx.x; i < n4; i += (long)nb*256){
    float4 v = ((const float4*)s)[i];
    h4 h;
    h[0]=(_Float16)v.x; h[1]=(_Float16)v.y; h[2]=(_Float16)v.z; h[3]=(_Float16)v.w;
    ((h4*)d)[i] = h;
  }
}
// W1/W3 -> interleaved W13 (16-row groups: [w1 16 | w3 16] per 32), plain, slots=experts
__device__ __forceinline__ void job_w13_plain(const float* __restrict__ w1,
    const float* __restrict__ w3, _Float16* __restrict__ dst, int nslot, int b0, int nb){
  const int K8 = C_/8;
  long total = (long)nslot * (2*H_) * K8;
  for (long i = (long)b0*256 + threadIdx.x; i < total; i += (long)nb*256){
    int kv = (int)(i & (K8-1));
    long rs = i >> 7;
    int r  = (int)(rs % (2*H_));
    int slot = (int)(rs / (2*H_));
    int gg = r >> 5, o = r & 31;
    const float* src = ((o<16)? w1 : w3) + (size_t)slot*PEsz + (size_t)(16*gg + (o&15))*C_ + kv*8;
    float4 v0 = *(const float4*)src, v1 = *(const float4*)(src+4);
    float vv[8] = {v0.x,v0.y,v0.z,v0.w,v1.x,v1.y,v1.z,v1.w};
    h8 hh;
#pragma unroll
    for (int jj=0;jj<8;++jj) hh[jj] = (_Float16)vv[jj];
    *(h8*)(dst + (size_t)slot*2*PEsz + (size_t)r*C_ + kv*8) = hh;
  }
}
// split variant with selected experts (2 slots)
__device__ __forceinline__ void job_w13_split_sel(const float* __restrict__ w1,
    const float* __restrict__ w3, int sel0, int sel1,
    _Float16* __restrict__ hi, _Float16* __restrict__ lo, int b0, int nb){
  const int K8 = C_/8;
  long total = 2L * (2*H_) * K8;
  for (long i = (long)b0*256 + threadIdx.x; i < total; i += (long)nb*256){
    int kv = (int)(i & (K8-1));
    long rs = i >> 7;
    int r  = (int)(rs % (2*H_));
    int slot = (int)(rs / (2*H_));
    int e = slot ? sel1 : sel0;
    int gg = r >> 5, o = r & 31;
    const float* src = ((o<16)? w1 : w3) + (size_t)e*PEsz + (size_t)(16*gg + (o&15))*C_ + kv*8;
    float4 v0 = *(const float4*)src, v1 = *(const float4*)(src+4);
    float vv[8] = {v0.x,v0.y,v0.z,v0.w,v1.x,v1.y,v1.z,v1.w};
    h8 hh, ll;
#pragma unroll
    for (int jj=0;jj<8;++jj){
      hh[jj] = (_Float16)vv[jj];
      ll[jj] = (_Float16)(vv[jj]-(float)hh[jj]);
    }
    size_t dof = (size_t)slot*2*PEsz + (size_t)r*C_ + kv*8;
    *(h8*)(hi + dof) = hh;
    *(h8*)(lo + dof) = ll;
  }
}
__device__ __forceinline__ void job_w2_split_sel(const float* __restrict__ w2,
    int sel0, int sel1, _Float16* __restrict__ hi, _Float16* __restrict__ lo, int b0, int nb){
  long per = (long)(PEsz/4);
  for (long i = (long)b0*256 + threadIdx.x; i < 2*per; i += (long)nb*256){
    int slot = (i >= per) ? 1 : 0;
    long ii = i - (long)slot*per;
    float4 v = ((const float4*)(w2 + (size_t)(slot?sel1:sel0)*PEsz))[ii];
    h4 h, L;
    h[0]=(_Float16)v.x; h[1]=(_Float16)v.y; h[2]=(_Float16)v.z; h[3]=(_Float16)v.w;
    L[0]=(_Float16)(v.x-(float)h[0]); L[1]=(_Float16)(v.y-(float)h[1]);
    L[2]=(_Float16)(v.z-(float)h[2]); L[3]=(_Float16)(v.w-(float)h[3]);
    ((h4*)(hi + (size_t)slot*PEsz))[ii] = h;
    ((h4*)(lo + (size_t)slot*PEsz))[ii] = L;
  }
}
// fold_w: Wp[e][k] = sum_c capgw[e][c]*outw[c][k]; bp[e] = sum_c outb[c]*capgw[e][c]
__device__ __forceinline__ void job_foldw(const float* __restrict__ outw,
    const float* __restrict__ capgw, const float* __restrict__ outb,
    float* __restrict__ Wp, float* __restrict__ bp, int b0){
  int e = b0 >> 2;
  int k = ((b0 & 3) << 8) + threadIdx.x;
  const float* cg = capgw + e*C_;
  float acc = 0.f;
  for (int c = 0; c < C_; ++c) acc += cg[c] * outw[(size_t)c*C_ + k];
  Wp[e*C_ + k] = acc;
  if ((b0 & 3) == 0){
    int wv = threadIdx.x >> 6, l = threadIdx.x & 63;
    const float* cg2 = capgw + wv*C_;
    float a2 = 0.f;
    for (int c = l; c < C_; c += 64) a2 += outb[c] * cg2[c];
#pragma unroll
    for (int off = 32; off; off >>= 1) a2 += __shfl_xor(a2, off);
    if (l == 0 && e == 0) bp[wv] = a2;
  }
}

// ---------------- convA: lang gating (inline, redundant per block) + phase-0 conversions ----------------
#define CVA_W13 1024
#define CVA_W2  512
#define CVA_X   256
#define CVA_TOT (CVA_W13+CVA_W2+CVA_X)
__global__ __launch_bounds__(256) void convA(
    const float* __restrict__ lang_embed, const float* __restrict__ gate_w,
    const float* __restrict__ gate_b, const int* __restrict__ language,
    const float* __restrict__ w1, const float* __restrict__ w3, const float* __restrict__ w2,
    const float* __restrict__ x,
    _Float16* __restrict__ w13hi, _Float16* __restrict__ w13lo,
    _Float16* __restrict__ w2hi, _Float16* __restrict__ w2lo,
    _Float16* __restrict__ xhi, _Float16* __restrict__ xlo,
    float* __restrict__ langP, int* __restrict__ counts)
{
  __shared__ float lds8[8];
  const int tid = threadIdx.x, w = tid>>6, l = tid&63;
  for (int p = 2*w; p < 2*w+2; ++p){
    int b = p>>2, e = p&3;
    const float* emb = lang_embed + (size_t)language[b]*C_;
    const float* gw  = gate_w + (size_t)e*C_;
    float acc = 0.f;
    for (int c = l; c < C_; c += 64) acc += emb[c]*gw[c];
#pragma unroll
    for (int off = 32; off; off >>= 1) acc += __shfl_xor(acc, off);
    if (l == 0) lds8[p] = acc + gate_b[e];
  }
  __syncthreads();
  int sel[2];
  for (int b = 0; b < 2; ++b){
    float z[4], m = -3.4e38f;
    for (int e = 0; e < 4; ++e){
      float g = jax_gumbel(0u, 1u, (uint32_t)(b*4 + e));
      z[e] = (lds8[b*4 + e] + g) * 0.5f;
      m = fmaxf(m, z[e]);
    }
    float y[4], sum = 0.f;
    for (int e = 0; e < 4; ++e){ y[e] = expf(z[e]-m); sum += y[e]; }
    for (int e = 0; e < 4; ++e) y[e] = y[e] / sum;
    int best = 0; float bv = y[0];
    for (int e = 1; e < 4; ++e) if (y[e] > bv){ bv = y[e]; best = e; }
    sel[b] = best;
    if (blockIdx.x == 0 && tid == 0){
      for (int e = 0; e < 4; ++e)
        langP[b*4 + e] = ((e == best) ? 1.0f : 0.0f) - y[e] + y[e];
    }
  }
  if (blockIdx.x == 0 && tid == 0){
    for (int e = 0; e < 4; ++e) counts[e] = 0;
  }
  int bid = blockIdx.x;
  if (bid < CVA_W13)                 job_w13_split_sel(w1, w3, sel[0], sel[1], w13hi, w13lo, bid, CVA_W13);
  else if (bid < CVA_W13+CVA_W2)     job_w2_split_sel(w2, sel[0], sel[1], w2hi, w2lo, bid-CVA_W13, CVA_W2);
  else                               job_split(x, xhi, xlo, (long)((size_t)N_*C_/4), bid-CVA_W13-CVA_W2, CVA_X);
}

// ============ deep-pipelined 256x128 split gate GEMM (ffn1_gate) ============
// Staging interleaved into compute phases (2 loads/phase), vmcnt(6),
// ONE barrier per K-tile. (r9-measured schedule)
__global__ __launch_bounds__(512,2) void gemm_gate_split(
    const _Float16* __restrict__ Ahi, const _Float16* __restrict__ Alo,
    const _Float16* __restrict__ Bhi, const _Float16* __restrict__ Blo,
    _Float16* __restrict__ Hhi, _Float16* __restrict__ Hlo)
{
  __shared__ __align__(16) char smem[147456];   // 3 x (A 32KB + B 16KB)
  const int tid = threadIdx.x, w = tid>>6, l = tid&63;
  const int lm = l&15, g = l>>4;
  const int wm = w>>1, wn = w&1;
  int bx = blockIdx.x, by = blockIdx.y;
  xcd_swizzle_cm(bx, by);
  const int n0 = bx<<7;
  const int m0 = by<<8;
  const size_t eoff = (m0 >= T_) ? (size_t)2*PEsz : 0;

  const _Float16* srcA[4]; const _Float16* srcB[2];
#pragma unroll
  for (int jj=0;jj<4;++jj){
    int c = jj*512 + tid, r = c>>3, s = c&7;
    int st = s ^ (r&7);
    srcA[jj] = (st<4 ? Ahi : Alo) + (size_t)(m0 + r)*C_ + ((st&3)<<3);
  }
#pragma unroll
  for (int jj=0;jj<2;++jj){
    int c = jj*512 + tid, r = c>>3, s = c&7;
    int st = s ^ (r&7);
    srcB[jj] = (st<4 ? Bhi : Blo) + eoff + (size_t)(n0 + r)*C_ + ((st&3)<<3);
  }

#define STGF(ts, bi) { \
    int k0 = (ts)<<5; \
    char* db = smem + (bi)*49152; \
    _Pragma("unroll") \
    for (int jj=0;jj<4;++jj) gload16(srcA[jj]+k0, db + (jj*512 + w*64)*16); \
    _Pragma("unroll") \
    for (int jj=0;jj<2;++jj) gload16(srcB[jj]+k0, db + 32768 + (jj*512 + w*64)*16); \
  }

  const int shi = (g ^ (lm&7)) << 4;
  int aoff[4], boff[4];
#pragma unroll
  for (int i=0;i<4;++i){
    aoff[i] = ((wm*64 + i*16 + lm)<<7) + shi;
    boff[i] = 32768 + ((wn*64 + i*16 + lm)<<7) + shi;
  }

  f4 acc[4][4] = {};
  const int nt = C_/32;   // 32
  STGF(0,0) STGF(1,1)
  for (int t=0; t<nt; ++t){
    const int bi = t%3;
    const bool ds = (t+2 < nt);
    const int k2 = (t+2)<<5;
    char* db2 = smem + ((t+2)%3)*49152;
    if (t+1 < nt) { asm volatile("s_waitcnt vmcnt(6)" ::: "memory"); }
    else          { asm volatile("s_waitcnt vmcnt(0)" ::: "memory"); }
    __builtin_amdgcn_s_barrier();
    asm volatile("" ::: "memory");
    const char* base = smem + bi*49152;
    // phase 1: stage A01 of t+2, compute hh
    if (ds){
      gload16(srcA[0]+k2, db2 + (0*512 + w*64)*16);
      gload16(srcA[1]+k2, db2 + (1*512 + w*64)*16);
    }
    h8 ah[4], bh[4];
#pragma unroll
    for (int i=0;i<4;++i){ ah[i] = *(const h8*)(base + aoff[i]); bh[i] = *(const h8*)(base + boff[i]); }
    __builtin_amdgcn_s_setprio(1);
#pragma unroll
    for (int mi=0;mi<4;++mi)
#pragma unroll
      for (int ni=0;ni<4;++ni)
        acc[mi][ni] = __builtin_amdgcn_mfma_f32_16x16x32_f16(ah[mi], bh[ni], acc[mi][ni],0,0,0);
    __builtin_amdgcn_s_setprio(0);
    // phase 2: stage A23 of t+2, compute ah*bl
    if (ds){
      gload16(srcA[2]+k2, db2 + (2*512 + w*64)*16);
      gload16(srcA[3]+k2, db2 + (3*512 + w*64)*16);
    }
    h8 bl[4];
#pragma unroll
    for (int i=0;i<4;++i) bl[i] = *(const h8*)(base + (boff[i]^64));
    __builtin_amdgcn_s_setprio(1);
#pragma unroll
    for (int mi=0;mi<4;++mi)
#pragma unroll
      for (int ni=0;ni<4;++ni)
        acc[mi][ni] = __builtin_amdgcn_mfma_f32_16x16x32_f16(ah[mi], bl[ni], acc[mi][ni],0,0,0);
    __builtin_amdgcn_s_setprio(0);
    // phase 3: stage B01 of t+2, compute al*bh
    if (ds){
      gload16(srcB[0]+k2, db2 + 32768 + (0*512 + w*64)*16);
      gload16(srcB[1]+k2, db2 + 32768 + (1*512 + w*64)*16);
    }
    h8 al[4];
#pragma unroll
    for (int i=0;i<4;++i) al[i] = *(const h8*)(base + (aoff[i]^64));
    __builtin_amdgcn_s_setprio(1);
#pragma unroll
    for (int mi=0;mi<4;++mi)
#pragma unroll
      for (int ni=0;ni<4;++ni)
        acc[mi][ni] = __builtin_amdgcn_mfma_f32_16x16x32_f16(al[mi], bh[ni], acc[mi][ni],0,0,0);
    __builtin_amdgcn_s_setprio(0);
    asm volatile("" ::: "memory");
  }
#undef STGF

#pragma unroll
  for (int mi=0;mi<4;++mi){
#pragma unroll
    for (int p=0;p<2;++p){
      int hc = ((n0 + wn*64)>>1) + p*16 + lm;
#pragma unroll
      for (int j=0;j<4;++j){
        int rl = wm*64 + mi*16 + (g<<2) + j;
        float s1 = acc[mi][2*p][j], s3 = acc[mi][2*p+1][j];
        float hval = s1/(1.f+expf(-s1))*s3;
        size_t row = (size_t)(m0 + rl);
        _Float16 hh = (_Float16)hval;
        Hhi[row*H_ + hc] = hh;
        Hlo[row*H_ + hc] = (_Float16)(hval - (float)hh);
      }
    }
  }
}

// ============ deep-pipelined 256x128 plain gate GEMM (ffn2_gate) ============
__global__ __launch_bounds__(512,2) void gemm_gate_plain(
    const _Float16* __restrict__ A, const _Float16* __restrict__ Bw,
    _Float16* __restrict__ Hout,
    const int* __restrict__ bmap_e, const int* __restrict__ bmap_s,
    const int* __restrict__ offs, const int* __restrict__ perm)
{
  __shared__ __align__(16) char smem[147456];
  const int tid = threadIdx.x, w = tid>>6, l = tid&63;
  const int lm = l&15, g = l>>4;
  const int wm = w>>1, wn = w&1;
  int bx = blockIdx.x, by = blockIdx.y;
  xcd_swizzle_cm(bx, by);
  const int e = bmap_e[by]; if (e<0) return;
  const int m0 = bmap_s[by];
  int v = offs[e+1]-m0; const int valid = v>256?256:v;
  const size_t eoff = (size_t)e*2*PEsz;
  const int n0 = bx<<7;

  const _Float16* srcA[4]; const _Float16* srcB[2];
#pragma unroll
  for (int jj=0;jj<4;++jj){
    int c = jj*512 + tid, r = c>>3, s = c&7;
    int st = s ^ (r&7);
    int ia = m0 + r; ia = (ia<N_) ? ia : (N_-1);
    srcA[jj] = A + (size_t)perm[ia]*C_ + (st<<3);
  }
#pragma unroll
  for (int jj=0;jj<2;++jj){
    int c = jj*512 + tid, r = c>>3, s = c&7;
    int st = s ^ (r&7);
    srcB[jj] = Bw + eoff + (size_t)(n0 + r)*C_ + (st<<3);
  }

#define STGF(ts, bi) { \
    int k0 = (ts)<<6; \
    char* db = smem + (bi)*49152; \
    _Pragma("unroll") \
    for (int jj=0;jj<4;++jj) gload16(srcA[jj]+k0, db + (jj*512 + w*64)*16); \
    _Pragma("unroll") \
    for (int jj=0;jj<2;++jj) gload16(srcB[jj]+k0, db + 32768 + (jj*512 + w*64)*16); \
  }

  const int shi = (g ^ (lm&7)) << 4;
  int aoff[4], boff[4];
#pragma unroll
  for (int i=0;i<4;++i){
    aoff[i] = ((wm*64 + i*16 + lm)<<7) + shi;
    boff[i] = 32768 + ((wn*64 + i*16 + lm)<<7) + shi;
  }

  f4 acc[4][4] = {};
  const int nt = C_/64;   // 16
  STGF(0,0) STGF(1,1)
  for (int t=0; t<nt; ++t){
    const int bi = t%3;
    const bool ds = (t+2 < nt);
    const int k2 = (t+2)<<6;
    char* db2 = smem + ((t+2)%3)*49152;
    if (t+1 < nt) { asm volatile("s_waitcnt vmcnt(6)" ::: "memory"); }
    else          { asm volatile("s_waitcnt vmcnt(0)" ::: "memory"); }
    __builtin_amdgcn_s_barrier();
    asm volatile("" ::: "memory");
    const char* base = smem + bi*49152;
#pragma unroll
    for (int kk=0;kk<2;++kk){
      if (ds){
        if (kk == 0){
          gload16(srcA[0]+k2, db2 + (0*512 + w*64)*16);
          gload16(srcA[1]+k2, db2 + (1*512 + w*64)*16);
          gload16(srcA[2]+k2, db2 + (2*512 + w*64)*16);
        } else {
          gload16(srcA[3]+k2, db2 + (3*512 + w*64)*16);
          gload16(srcB[0]+k2, db2 + 32768 + (0*512 + w*64)*16);
          gload16(srcB[1]+k2, db2 + 32768 + (1*512 + w*64)*16);
        }
      }
      h8 af[4], bf[4];
      const int x = kk<<6;
#pragma unroll
      for (int i=0;i<4;++i){ af[i] = *(const h8*)(base + (aoff[i]^x)); bf[i] = *(const h8*)(base + (boff[i]^x)); }
      __builtin_amdgcn_s_setprio(1);
#pragma unroll
      for (int mi=0;mi<4;++mi)
#pragma unroll
        for (int ni=0;ni<4;++ni)
          acc[mi][ni] = __builtin_amdgcn_mfma_f32_16x16x32_f16(af[mi], bf[ni], acc[mi][ni],0,0,0);
      __builtin_amdgcn_s_setprio(0);
    }
    asm volatile("" ::: "memory");
  }
#undef STGF

#pragma unroll
  for (int mi=0;mi<4;++mi){
#pragma unroll
    for (int p=0;p<2;++p){
      int hc = ((n0 + wn*64)>>1) + p*16 + lm;
#pragma unroll
      for (int j=0;j<4;++j){
        int rl = wm*64 + mi*16 + (g<<2) + j;
        if (rl >= valid) continue;
        float s1 = acc[mi][2*p][j], s3 = acc[mi][2*p+1][j];
        Hout[(size_t)(m0 + rl)*H_ + hc] = (_Float16)(s1/(1.f+expf(-s1))*s3);
      }
    }
  }
}

// ---------------- unified pipelined GEMM body (128x128, 2-barrier vmcnt(8) schedule) ----------------
// EPI: 1 f16 hi/lo (+opt bias), 2 scatter-add
// EXPM: 0 none, 1 lang slot by m-block, 3 grouped rows + linear A
template<int EPI, int NSEG, int EXPM>
__device__ __forceinline__ void gemm8_body(
    char* smem,
    const _Float16* __restrict__ A0, const _Float16* __restrict__ A1,
    const _Float16* __restrict__ B0, const _Float16* __restrict__ B1,
    const float* __restrict__ bias, float* __restrict__ Cf32,
    _Float16* __restrict__ O0, _Float16* __restrict__ O1,
    const int* __restrict__ bmap_e, const int* __restrict__ bmap_s,
    const int* __restrict__ offs, const int* __restrict__ perm,
    int M, int K, int Nw, size_t bstride_e, int bx, int by)
{
  const int tid = threadIdx.x, w = tid>>6, l = tid&63;
  const int lm = l&15, g = l>>4;
  const int wm = w>>1, wn = w&1;
  const int n0 = bx<<7;
  int m0, valid = 128; size_t eoff = 0;
  if constexpr (EXPM==3){
    int e = bmap_e[by]; if (e<0) return;
    m0 = bmap_s[by];
    int v = offs[e+1]-m0; valid = v>128?128:v;
    eoff = (size_t)e*bstride_e;
  } else {
    m0 = by<<7;
    if constexpr (EXPM==1) eoff = (m0>=T_) ? bstride_e : 0;
  }
  const int cAe = (((tid&7) ^ ((tid>>3)&7)) << 3);
  size_t rbA[4], rbB[4];
#pragma unroll
  for (int j=0;j<4;++j){
    int r = (j<<5) + (tid>>3);
    int ia = m0 + r;
    if constexpr (EXPM==3){ ia = (ia < N_) ? ia : (N_-1); }
    else { if (ia > M-1) ia = M-1; }
    rbA[j] = (size_t)ia*K + cAe;
    rbB[j] = eoff + (size_t)(n0+r)*K + cAe;
  }
  const int tps = K>>6, nt = NSEG*tps;

#define STAGE8(tt, cc) { \
    int sg = 0; \
    if constexpr (NSEG==3){ sg = ((tt)>=2*tps) ? 2 : (((tt)>=tps)?1:0); } \
    const _Float16* Asrc = (sg==1) ? A1 : A0; \
    const _Float16* Bsrc = (sg==2) ? B1 : B0; \
    int kk0 = ((tt) - sg*tps)<<6; \
    char* db = smem + (cc)*32768 + w*1024; \
    _Pragma("unroll") \
    for (int j=0;j<4;++j) gload16(Asrc + rbA[j] + kk0, db + j*4096); \
    _Pragma("unroll") \
    for (int j=0;j<4;++j) gload16(Bsrc + rbB[j] + kk0, db + 16384 + j*4096); \
  }

  int aoff[2][4], boff[2][4];
#pragma unroll
  for (int kk=0;kk<2;++kk){
#pragma unroll
    for (int i=0;i<4;++i){
      int ra = wm*64 + i*16 + lm;
      aoff[kk][i] = (ra<<7) + (((kk<<6)+(g<<4)) ^ ((ra&7)<<4));
      int rb = wn*64 + i*16 + lm;
      boff[kk][i] = (rb<<7) + (((kk<<6)+(g<<4)) ^ ((rb&7)<<4));
    }
  }

  f4 acc[4][4] = {};
  STAGE8(0, 0)
  for (int t=0; t<nt; ++t){
    const int c = t&1;
    if (t+1 < nt){
      STAGE8(t+1, c^1)
      asm volatile("s_waitcnt vmcnt(8)" ::: "memory");
    } else {
      asm volatile("s_waitcnt vmcnt(0)" ::: "memory");
    }
    __builtin_amdgcn_s_barrier();
    const char* Ab = smem + c*32768;
    const char* Bb = Ab + 16384;
#pragma unroll
    for (int kk=0;kk<2;++kk){
      h8 af[4], bf[4];
#pragma unroll
      for (int i=0;i<4;++i){
        af[i] = *(const h8*)(Ab + aoff[kk][i]);
        bf[i] = *(const h8*)(Bb + boff[kk][i]);
      }
      __builtin_amdgcn_s_setprio(1);
#pragma unroll
      for (int mi=0;mi<4;++mi)
#pragma unroll
        for (int ni=0;ni<4;++ni)
          acc[mi][ni] = __builtin_amdgcn_mfma_f32_16x16x32_f16(af[mi], bf[ni], acc[mi][ni],0,0,0);
      __builtin_amdgcn_s_setprio(0);
      __builtin_amdgcn_s_barrier();
    }
  }

#pragma unroll
  for (int mi=0;mi<4;++mi){
    const int rl0 = wm*64 + mi*16 + (g<<2);
#pragma unroll
    for (int ni=0;ni<4;++ni){
      int col = n0 + wn*64 + ni*16 + lm;
#pragma unroll
      for (int j=0;j<4;++j){
        int rl = rl0 + j;
        float vv = acc[mi][ni][j];
        if constexpr (EPI==1){
          int grow = m0 + rl;
          if (grow < M){
            float vb = vv + (bias ? bias[col] : 0.f);
            _Float16 hh = (_Float16)vb;
            O0[(size_t)grow*Nw + col] = hh;
            O1[(size_t)grow*Nw + col] = (_Float16)(vb - (float)hh);
          }
        } else {
          if (rl < valid){
            int orig = perm[m0 + rl];
            size_t o = (size_t)orig*C_ + col;
            Cf32[o] = (float)O0[o] + (float)O1[o] + vv;
          }
        }
      }
    }
  }
#undef STAGE8
}

template<int EPI, int NSEG, int EXPM>
__global__ __launch_bounds__(256,2) void gemm8(
    const _Float16* __restrict__ A0, const _Float16* __restrict__ A1,
    const _Float16* __restrict__ B0, const _Float16* __restrict__ B1,
    const float* __restrict__ bias, float* __restrict__ Cf32,
    _Float16* __restrict__ O0, _Float16* __restrict__ O1,
    const int* __restrict__ bmap_e, const int* __restrict__ bmap_s,
    const int* __restrict__ offs, const int* __restrict__ perm,
    int M, int K, int Nw, size_t bstride_e)
{
  __shared__ __align__(16) char smem[65536];
  int bx = blockIdx.x, by = blockIdx.y;
  xcd_swizzle_cm(bx, by);
  gemm8_body<EPI,NSEG,EXPM>(smem, A0,A1,B0,B1,bias,Cf32,O0,O1,
                            bmap_e,bmap_s,offs,perm,M,K,Nw,bstride_e,bx,by);
}

// ---------------- ffn1_out (gemm8<1,3,1>) fused with phase-2 weight conversions ----------------
__global__ __launch_bounds__(256,2) void ffn1_out_fused(
    const _Float16* __restrict__ Hbh, const _Float16* __restrict__ Hbl,
    const _Float16* __restrict__ w2hi, const _Float16* __restrict__ w2lo,
    _Float16* __restrict__ Fh, _Float16* __restrict__ Fl,
    const float* __restrict__ in_w,
    const float* __restrict__ cap_w1, const float* __restrict__ cap_w3,
    const float* __restrict__ caption,
    _Float16* __restrict__ inwh, _Float16* __restrict__ inwl,
    _Float16* __restrict__ capw13,
    _Float16* __restrict__ caph, _Float16* __restrict__ capl)
{
  __shared__ __align__(16) char smem[65536];
  int id = blockIdx.x;
  if (id < 256){
    gemm8_body<1,3,1>(smem, Hbh, Hbl, w2hi, w2lo, nullptr, nullptr, Fh, Fl,
                      nullptr,nullptr,nullptr,nullptr, N_, H_, C_, PEsz, id&7, id>>3);
  } else {
    int cid = id - 256;                    // 512 conversion blocks
    if (cid < 352)      job_w13_plain(cap_w1, cap_w3, capw13, 4, cid, 352);
    else if (cid < 496) job_split(in_w, inwh, inwl, (long)(3*CC_/4), cid-352, 144);
    else                job_split(caption, caph, capl, (long)((size_t)B_*S_*C_/4), cid-496, 16);
  }
}

// ---------------- Q + KV projections + fold_w in one dispatch ----------------
__global__ __launch_bounds__(256,2) void gemm_qkv(
    const _Float16* __restrict__ Fh, const _Float16* __restrict__ Fl,
    const _Float16* __restrict__ caph, const _Float16* __restrict__ capl,
    const _Float16* __restrict__ inwh, const _Float16* __restrict__ inwl,
    const float* __restrict__ in_b,
    _Float16* __restrict__ Qh, _Float16* __restrict__ Ql,
    _Float16* __restrict__ KVh, _Float16* __restrict__ KVl,
    const float* __restrict__ out_w, const float* __restrict__ cap_gw,
    const float* __restrict__ out_b, float* __restrict__ Wp, float* __restrict__ bp)
{
  __shared__ __align__(16) char smem[65536];
  int id = blockIdx.x;
  if (id < 256){
    gemm8_body<1,3,0>(smem, Fh, Fl, inwh, inwl, in_b, nullptr, Qh, Ql,
                      nullptr,nullptr,nullptr,nullptr, N_, C_, C_, 0, id&7, id>>3);
  } else if (id < 288){
    int cid = id - 256;                    // KV: grid (16,2)
    gemm8_body<1,3,0>(smem, caph, capl, inwh + CC_, inwl + CC_, in_b + C_,
                      nullptr, KVh, KVl, nullptr,nullptr,nullptr,nullptr,
                      B_*S_, C_, 2*C_, 0, cid & 15, cid >> 4);
  } else {
    job_foldw(out_w, cap_gw, out_b, Wp, bp, id-288);   // 16 blocks
  }
}

// ---------------- MFMA cross attention (flattened grid) + capw2 conversion ----------------
#define SP5 5
#define KSTR 136
#define VSTR 104
__global__ __launch_bounds__(256) void attn_fused(
    const _Float16* __restrict__ Qh, const _Float16* __restrict__ Ql,
    const _Float16* __restrict__ KVh, const _Float16* __restrict__ KVl,
    _Float16* __restrict__ AOh, _Float16* __restrict__ AOl,
    const float* __restrict__ cap_w2, _Float16* __restrict__ capw2f)
{
  __shared__ __align__(16) _Float16 Usm[2*128*VSTR];
  __shared__ __align__(16) _Float16 Psm[2*64*VSTR];
  int id = blockIdx.x;
  if (id >= 512){ job_plain(cap_w2, capw2f, (long)(4*PEsz/4), id-512, 128); return; }
  _Float16* Kh_s = Usm;
  _Float16* Kl_s = Usm + 128*VSTR;
  _Float16* VTh  = Usm;
  _Float16* VTl  = Usm + 128*VSTR;
  _Float16* Ph   = Psm;
  _Float16* Pl   = Psm + 64*VSTR;

  const int tid = threadIdx.x;
  const int w = tid>>6, l = tid&63, lm = l&15, g = l>>4;
  const int b = id >> 8, h = (id >> 5) & 7, q0 = (id & 31) << 6;
  const float scale = 0.08838834764831845f;

  for (int i = tid; i < 64*VSTR; i += 256) ((uint32_t*)Psm)[i] = 0;
  {
    int oct = tid & 15, s0 = tid >> 4;
    for (int s = s0; s < 80; s += 16){
      h8 vh = {}, vl = {};
      if (s < S_){
        size_t ga = ((size_t)(b*S_ + s))*(2*C_) + h*HD_ + oct*8;
        vh = *(const h8*)(KVh + ga);
        vl = *(const h8*)(KVl + ga);
      }
      *(h8*)(Kh_s + s*KSTR + oct*8) = vh;
      *(h8*)(Kl_s + s*KSTR + oct*8) = vl;
    }
  }
  h8 qh[4], ql[4];
  {
    size_t qrow = (size_t)(b*T_ + q0 + w*16 + lm);
    const _Float16* qph = Qh + qrow*C_ + h*HD_ + g*8;
    const _Float16* qpl = Ql + qrow*C_ + h*HD_ + g*8;
#pragma unroll
    for (int ks=0; ks<4; ++ks){ qh[ks] = *(const h8*)(qph + ks*32); ql[ks] = *(const h8*)(qpl + ks*32); }
  }
  __syncthreads();

  f4 sc[SP5] = {};
#pragma unroll
  for (int ks=0; ks<4; ++ks){
#pragma unroll
    for (int nt=0; nt<SP5; ++nt){
      h8 kh = *(const h8*)(Kh_s + (nt*16+lm)*KSTR + ks*32 + g*8);
      h8 kl = *(const h8*)(Kl_s + (nt*16+lm)*KSTR + ks*32 + g*8);
      sc[nt] = __builtin_amdgcn_mfma_f32_16x16x32_f16(qh[ks], kh, sc[nt],0,0,0);
      sc[nt] = __builtin_amdgcn_mfma_f32_16x16x32_f16(ql[ks], kh, sc[nt],0,0,0);
      sc[nt] = __builtin_amdgcn_mfma_f32_16x16x32_f16(qh[ks], kl, sc[nt],0,0,0);
    }
  }

  float mx[4] = {-3e38f,-3e38f,-3e38f,-3e38f};
#pragma unroll
  for (int nt=0; nt<SP5; ++nt){
    bool valid = (nt*16+lm) < S_;
#pragma unroll
    for (int j=0;j<4;++j){
      float v = valid ? sc[nt][j]*scale : -3e38f;
      sc[nt][j] = v;
      mx[j] = fmaxf(mx[j], v);
    }
  }
#pragma unroll
  for (int off=1; off<16; off<<=1){
#pragma unroll
    for (int j=0;j<4;++j) mx[j] = fmaxf(mx[j], __shfl_xor(mx[j], off));
  }
  float sm[4] = {0,0,0,0};
#pragma unroll
  for (int nt=0; nt<SP5; ++nt){
    bool valid = (nt*16+lm) < S_;
#pragma unroll
    for (int j=0;j<4;++j){
      float p = valid ? expf(sc[nt][j]-mx[j]) : 0.f;
      sc[nt][j] = p; sm[j] += p;
    }
  }
#pragma unroll
  for (int off=1; off<16; off<<=1){
#pragma unroll
    for (int j=0;j<4;++j) sm[j] += __shfl_xor(sm[j], off);
  }
#pragma unroll
  for (int nt=0; nt<SP5; ++nt){
#pragma unroll
    for (int j=0;j<4;++j){
      int col = nt*16 + lm;
      if (col < S_){
        float p = sc[nt][j] / sm[j];
        int row = w*16 + g*4 + j;
        _Float16 ph = (_Float16)p;
        Ph[row*VSTR + col] = ph;
        Pl[row*VSTR + col] = (_Float16)(p - (float)ph);
      }
    }
  }
  __syncthreads();

  for (int i = tid; i < 128*VSTR; i += 256) ((uint32_t*)Usm)[i] = 0;
  __syncthreads();
  {
    int oct = tid & 15, s0 = tid >> 4;
    for (int s = s0; s < S_; s += 16){
      size_t ga = ((size_t)(b*S_ + s))*(2*C_) + C_ + h*HD_ + oct*8;
      h8 vh = *(const h8*)(KVh + ga);
      h8 vl = *(const h8*)(KVl + ga);
#pragma unroll
      for (int i2=0;i2<8;++i2){
        VTh[(oct*8+i2)*VSTR + s] = vh[i2];
        VTl[(oct*8+i2)*VSTR + s] = vl[i2];
      }
    }
  }
  __syncthreads();

  h8 pah[3], pal[3];
#pragma unroll
  for (int ks=0;ks<3;++ks){
    pah[ks] = *(const h8*)(Ph + (w*16+lm)*VSTR + ks*32 + g*8);
    pal[ks] = *(const h8*)(Pl + (w*16+lm)*VSTR + ks*32 + g*8);
  }
#pragma unroll
  for (int nt=0; nt<8; ++nt){
    f4 o = {};
#pragma unroll
    for (int ks=0;ks<3;++ks){
      h8 vh = *(const h8*)(VTh + (nt*16+lm)*VSTR + ks*32 + g*8);
      h8 vl = *(const h8*)(VTl + (nt*16+lm)*VSTR + ks*32 + g*8);
      o = __builtin_amdgcn_mfma_f32_16x16x32_f16(pah[ks], vh, o,0,0,0);
      o = __builtin_amdgcn_mfma_f32_16x16x32_f16(pal[ks], vh, o,0,0,0);
      o = __builtin_amdgcn_mfma_f32_16x16x32_f16(pah[ks], vl, o,0,0,0);
    }
#pragma unroll
    for (int j=0;j<4;++j){
      size_t orow = (size_t)(b*T_ + q0 + w*16 + g*4 + j);
      size_t oa = orow*C_ + h*HD_ + nt*16 + lm;
      _Float16 hh = (_Float16)o[j];
      AOh[oa] = hh;
      AOl[oa] = (_Float16)(o[j] - (float)hh);
    }
  }
}

// ---------------- caption gating from AO (hi/lo) via folded W' ----------------
__global__ __launch_bounds__(256) void cap_gate(
    const _Float16* __restrict__ AOh, const _Float16* __restrict__ AOl,
    const float* __restrict__ Wp, const float* __restrict__ bp,
    const float* __restrict__ gb,
    int* __restrict__ cap_sel, float* __restrict__ capP, int* __restrict__ counts)
{
  int tid = threadIdx.x, wave = tid >> 6, lane = tid & 63;
  for (int r = 0; r < 2; ++r){
    int row = (blockIdx.x << 3) + (wave << 1) + r;
    float av[16];
#pragma unroll
    for (int i = 0; i < 16; ++i){
      int c = lane + (i << 6);
      av[i] = (float)AOh[(size_t)row*C_ + c] + (float)AOl[(size_t)row*C_ + c];
    }
    float lg[E_];
#pragma unroll
    for (int e = 0; e < E_; ++e){
      const float* wv = Wp + (size_t)e * C_;
      float p = 0.f;
#pragma unroll
      for (int i = 0; i < 16; ++i) p += av[i] * wv[lane + (i << 6)];
#pragma unroll
      for (int off = 32; off; off >>= 1) p += __shfl_xor(p, off);
      lg[e] = p + bp[e] + gb[e];
    }
    if (lane == 0){
      float z[E_], m = -3.4e38f;
      for (int e = 0; e < E_; ++e){
        float gmb = jax_gumbel(0u, 2u, (uint32_t)(row*E_ + e));
        z[e] = (lg[e] + gmb) * 0.5f;
        m = fmaxf(m, z[e]);
      }
      float y[E_], sum = 0.f;
      for (int e = 0; e < E_; ++e){ y[e] = expf(z[e] - m); sum += y[e]; }
      for (int e = 0; e < E_; ++e) y[e] = y[e] / sum;
      int best = 0; float bv = y[0];
      for (int e = 1; e < E_; ++e) if (y[e] > bv){ bv = y[e]; best = e; }
      cap_sel[row] = best;
      atomicAdd(&counts[best], 1);
      for (int e = 0; e < E_; ++e)
        capP[(size_t)row*E_ + e] = ((e == best) ? 1.0f : 0.0f) - y[e] + y[e];
    }
  }
}

// ---------------- finalize: groups + perm scatter (block 0) + loss (block 1) ----------------
__global__ __launch_bounds__(256) void finalize(
    const int* __restrict__ counts, const int* __restrict__ cap_sel,
    int* __restrict__ offs,
    int* __restrict__ bmap_e, int* __restrict__ bmap_s,
    int* __restrict__ bmap_e2, int* __restrict__ bmap_s2,
    int* __restrict__ perm,
    const float* __restrict__ capP, const float* __restrict__ langP,
    float* __restrict__ out_loss)
{
  __shared__ int loffs[5];
  __shared__ int lcur[4];
  __shared__ float red[4][256];
  int tid = threadIdx.x;
  if (blockIdx.x == 0){
    if (tid == 0){
      loffs[0] = 0;
      for (int e = 0; e < E_; ++e){ loffs[e+1] = loffs[e] + counts[e]; lcur[e] = loffs[e]; }
      for (int e = 0; e < E_+1; ++e) offs[e] = loffs[e];
      int idx = 0;
      for (int e = 0; e < E_; ++e)
        for (int s = loffs[e]; s < loffs[e+1]; s += 128){ bmap_e[idx] = e; bmap_s[idx] = s; ++idx; }
      for (; idx < MAXGB; ++idx) bmap_e[idx] = -1;
      int idx2 = 0;
      for (int e = 0; e < E_; ++e)
        for (int s = loffs[e]; s < loffs[e+1]; s += 256){ bmap_e2[idx2] = e; bmap_s2[idx2] = s; ++idx2; }
      for (; idx2 < MAXGB2; ++idx2) bmap_e2[idx2] = -1;
    }
    __syncthreads();
    for (int row = tid; row < N_; row += 256){
      int e = cap_sel[row];
      int pos = atomicAdd(&lcur[e], 1);
      perm[pos] = row;
    }
  } else {
    float p0=0.f, p1=0.f, p2=0.f, p3=0.f;
    for (int r = tid; r < N_; r += 256){
      const float* p = capP + (size_t)r*E_;
      p0 += p[0]; p1 += p[1]; p2 += p[2]; p3 += p[3];
    }
    red[0][tid]=p0; red[1][tid]=p1; red[2][tid]=p2; red[3][tid]=p3;
    __syncthreads();
    for (int s = 128; s > 0; s >>= 1){
      if (tid < s){
        red[0][tid]+=red[0][tid+s]; red[1][tid]+=red[1][tid+s];
        red[2][tid]+=red[2][tid+s]; red[3][tid]+=red[3][tid+s];
      }
      __syncthreads();
    }
    if (tid == 0){
      float loss = 0.f;
      for (int e = 0; e < E_; ++e){
        float ul = (langP[e] + langP[E_ + e]) * 0.5f;
        loss += ul * logf(ul + 1e-10f);
      }
      for (int e = 0; e < E_; ++e){
        float uc = red[e][0] * (1.0f / N_);
        loss += uc * logf(uc + 1e-10f);
      }
      out_loss[0] = loss;
    }
  }
}

// ---------------- host launch ----------------
extern "C" void kernel_launch(void* const* d_in, const int* in_sizes, int n_in,
                              void* d_out, int out_size, void* d_ws, size_t ws_size,
                              hipStream_t stream)
{
  const float* x          = (const float*)d_in[0];
  const float* caption    = (const float*)d_in[2];
  const int*   language   = (const int*)  d_in[3];
  const float* lang_embed = (const float*)d_in[4];
  const float* lang_gw    = (const float*)d_in[5];
  const float* lang_gb    = (const float*)d_in[6];
  const float* lang_w1    = (const float*)d_in[7];
  const float* lang_w2    = (const float*)d_in[8];
  const float* lang_w3    = (const float*)d_in[9];
  const float* in_w       = (const float*)d_in[10];
  const float* in_b       = (const float*)d_in[11];
  const float* out_w      = (const float*)d_in[12];
  const float* out_b      = (const float*)d_in[13];
  const float* cap_gw     = (const float*)d_in[14];
  const float* cap_gb     = (const float*)d_in[15];
  const float* cap_w1     = (const float*)d_in[16];
  const float* cap_w2     = (const float*)d_in[17];
  const float* cap_w3     = (const float*)d_in[18];
  float* out = (float*)d_out;

  const size_t NC = (size_t)N_*C_;
  const size_t NHe = (size_t)N_*H_;
  const size_t KVel = (size_t)B_*S_*2*C_;
  const size_t CAPel = (size_t)B_*S_*C_;

  char* base = (char*)d_ws;
  size_t cur = 0;
  auto alloc = [&](size_t bytes)->char*{
    char* p = base + cur;
    cur += (bytes + 255) & ~(size_t)255;
    return p;
  };
  _Float16* Qh = (_Float16*)alloc(NC*2);
  _Float16* Ql = (_Float16*)alloc(NC*2);
  char* kvreg = alloc(KVel*4);
  _Float16* KVh = (_Float16*)kvreg;
  _Float16* KVl = KVh + KVel;
  float* capP   = (float*)alloc((size_t)N_*E_*4);
  float* langP  = (float*)alloc(64);
  float* Wp     = (float*)alloc(E_*C_*4);
  float* bp     = (float*)alloc(64);
  int* cap_sel  = (int*)alloc(N_*4);
  int* counts   = (int*)alloc(64);
  int* offs     = (int*)alloc(64);
  int* bmap_e   = (int*)alloc(MAXGB*4);
  int* bmap_s   = (int*)alloc(MAXGB*4);
  int* bmap_e2  = (int*)alloc(MAXGB2*4);
  int* bmap_s2  = (int*)alloc(MAXGB2*4);
  int* perm     = (int*)alloc(N_*4);
  _Float16* xAO_hi = (_Float16*)alloc(NC*2);      // x_hi, then AO_hi
  _Float16* xAO_lo = (_Float16*)alloc(NC*2);
  _Float16* cap_hi = (_Float16*)alloc(CAPel*2);
  _Float16* cap_lo = (_Float16*)alloc(CAPel*2);
  _Float16* Hb_hi  = (_Float16*)alloc(NHe*2);     // stage-1 hidden hi, then H2
  _Float16* Hb_lo  = (_Float16*)alloc(NHe*2);
  _Float16* F_hi   = (_Float16*)alloc(NC*2);
  _Float16* F_lo   = (_Float16*)alloc(NC*2);
  _Float16* Wreg = (_Float16*)alloc(2*( (size_t)3*CC_*2 + CC_*2 + 3*4*PEsz ));
  // phase-1 (lang): w13 split [0,8P), w2 split [8P,12P)
  _Float16* w13hi = Wreg;
  _Float16* w13lo = Wreg + 4*PEsz;
  _Float16* w2hi  = Wreg + 8*PEsz;
  _Float16* w2lo  = Wreg + 10*PEsz;
  // phase-2 in FRESH regions (riders write these while w13/w2 still live):
  _Float16* inw_hi  = Wreg + 12*PEsz;
  _Float16* inw_lo  = inw_hi + 3*CC_;
  _Float16* capw13f = Wreg + 12*PEsz + 6*CC_;       // 8*PEsz
  _Float16* capw2f  = capw13f + 8*PEsz;             // 4*PEsz

  // 1) phase-0 conversions (+ inline language gating)
  convA<<<CVA_TOT, 256, 0, stream>>>(
      lang_embed, lang_gw, lang_gb, language,
      lang_w1, lang_w3, lang_w2, x,
      w13hi, w13lo, w2hi, w2lo, xAO_hi, xAO_lo, langP, counts);

  // 2) ffn1 gate (pure, interleaved-stage single-barrier schedule)
  gemm_gate_split<<<dim3((2*H_)/128, N_/256), 512, 0, stream>>>(
      xAO_hi, xAO_lo, w13hi, w13lo, Hb_hi, Hb_lo);

  // 3) ffn1 out (2-barrier vmcnt(8) body) + capw13/inw/caption riders
  ffn1_out_fused<<<768, 256, 0, stream>>>(
      Hb_hi, Hb_lo, w2hi, w2lo, F_hi, F_lo,
      in_w, cap_w1, cap_w3, caption,
      inw_hi, inw_lo, capw13f, cap_hi, cap_lo);

  // 4) Q + KV projections + fold_w (W' = cap_gw . out_w)
  gemm_qkv<<<304, 256, 0, stream>>>(
      F_hi, F_lo, cap_hi, cap_lo, inw_hi, inw_lo, in_b,
      Qh, Ql, KVh, KVl, out_w, cap_gw, out_b, Wp, bp);

  // 5) attention + capw2 riders
  attn_fused<<<640, 256, 0, stream>>>(Qh, Ql, KVh, KVl, xAO_hi, xAO_lo, cap_w2, capw2f);

  // 6) caption gating directly from AO via W'
  cap_gate<<<N_/8, 256, 0, stream>>>(xAO_hi, xAO_lo, Wp, bp, cap_gb, cap_sel, capP, counts);

  // 7) groups + perm + loss
  finalize<<<2, 256, 0, stream>>>(counts, cap_sel, offs, bmap_e, bmap_s,
                                  bmap_e2, bmap_s2, perm, capP, langP, out + NC);

  // 8) ffn2 gate
  _Float16* H2 = Hb_hi;
  gemm_gate_plain<<<dim3((2*H_)/128, MAXGB2), 512, 0, stream>>>(
      F_hi, capw13f, H2, bmap_e2, bmap_s2, offs, perm);

  // 9) ffn2 out + final sum scatter
  gemm8<2,1,3><<<dim3(C_/128, MAXGB), 256, 0, stream>>>(
      H2, nullptr, capw2f, nullptr, nullptr, out, F_hi, F_lo,
      bmap_e, bmap_s, offs, perm, N_, H_, C_, PEsz);
}